// Round 15
// baseline (655.773 us; speedup 1.0000x reference)
//
#include <hip/hip_runtime.h>
#include <hip/hip_bf16.h>

#define DEV static __device__ __forceinline__

typedef __attribute__((ext_vector_type(16))) float f32x16;
typedef __attribute__((ext_vector_type(8)))  short bf16x8;
typedef __attribute__((ext_vector_type(8)))  int   i32x8;

#if defined(__has_builtin)
#  if __has_builtin(__builtin_amdgcn_cvt_pk_fp8_f32) && __has_builtin(__builtin_amdgcn_cvt_f32_fp8)
#    define HW_FP8 1
#  endif
#endif

DEV ushort f2bf(float f){
  union { float f; unsigned u; } v; v.f = f;
  return (ushort)((v.u + 0x7FFFu + ((v.u >> 16) & 1u)) >> 16);
}
DEV float bf2f(ushort u){
  union { unsigned u; float f; } v; v.u = ((unsigned)u) << 16;
  return v.f;
}

DEV unsigned char f2e4m3_sw(float f){
  union { float f; unsigned u; } v; v.f = f;
  unsigned s = (v.u >> 24) & 0x80;
  float a = fabsf(f);
  if (a >= 448.f) return s | 0x7E;
  if (a < 0.0009765625f) return (unsigned char)s;
  if (a < 0.015625f) {
    int m = (int)rintf(a * 512.f);
    return (unsigned char)(s | (m >= 8 ? 8 : m));
  }
  unsigned ab = v.u & 0x7FFFFFFF;
  unsigned r = ab + 0x0007FFFF + ((ab >> 20) & 1);
  unsigned e = (r >> 23) - 127 + 7;
  unsigned m = (r >> 20) & 7;
  if (e > 15 || (e == 15 && m > 6)) return s | 0x7E;
  return (unsigned char)(s | (e << 3) | m);
}
DEV float e4m32f_sw(unsigned char c){
  unsigned e = (c >> 3) & 15, m = c & 7;
  float v;
  if (e) { union { unsigned u; float f; } w; w.u = ((e + 120u) << 23) | (m << 20); v = w.f; }
  else v = (float)m * 0.001953125f;
  return (c & 0x80) ? -v : v;
}

DEV unsigned pack4_fp8(float a, float b, float c, float d){
#ifdef HW_FP8
  int v = __builtin_amdgcn_cvt_pk_fp8_f32(a, b, 0, false);
  v = __builtin_amdgcn_cvt_pk_fp8_f32(c, d, v, true);
  return (unsigned)v;
#else
  return (unsigned)f2e4m3_sw(a) | ((unsigned)f2e4m3_sw(b) << 8)
       | ((unsigned)f2e4m3_sw(c) << 16) | ((unsigned)f2e4m3_sw(d) << 24);
#endif
}
DEV unsigned char enc_fp8(float a){
#ifdef HW_FP8
  return (unsigned char)(__builtin_amdgcn_cvt_pk_fp8_f32(a, a, 0, false) & 0xFF);
#else
  return f2e4m3_sw(a);
#endif
}
template<int SEL>
DEV float dec_fp8(unsigned u){
#ifdef HW_FP8
  return __builtin_amdgcn_cvt_f32_fp8((int)u, SEL);
#else
  return e4m32f_sw((u >> (SEL * 8)) & 0xFF);
#endif
}

// async global->LDS, 16B per lane; LDS dest is wave-uniform base + lane*16.
DEV void gload16(const void* g, void* l) {
  __builtin_amdgcn_global_load_lds(
      (const __attribute__((address_space(1))) unsigned*)g,
      (__attribute__((address_space(3))) unsigned*)l, 16, 0, 0);
}

// MX-scaled fp8 MFMA, K=64, unit scales (E8M0 127 = 2^0).
DEV f32x16 mfma64(i32x8 a, i32x8 b, f32x16 c){
  return __builtin_amdgcn_mfma_scale_f32_32x32x64_f8f6f4(
      a, b, c, 0 /*cbsz: fp8*/, 0 /*blgp: fp8*/, 0, 127, 0, 127);
}

// ---------------------------------------------------------------------------
// Elementwise f32 -> bf16 (Wq/Wk only).
// ---------------------------------------------------------------------------
__global__ __launch_bounds__(256)
void cvt_bf16(const float* __restrict__ src, ushort* __restrict__ dst, long n8)
{
  const long stride = (long)gridDim.x * 256;
  for (long i = (long)blockIdx.x * 256 + threadIdx.x; i < n8; i += stride) {
    const float4 a = *(const float4*)(src + i * 8);
    const float4 b = *(const float4*)(src + i * 8 + 4);
    union { ushort u[8]; uint4 v; } pk;
    pk.u[0] = f2bf(a.x); pk.u[1] = f2bf(a.y); pk.u[2] = f2bf(a.z); pk.u[3] = f2bf(a.w);
    pk.u[4] = f2bf(b.x); pk.u[5] = f2bf(b.y); pk.u[6] = f2bf(b.z); pk.u[7] = f2bf(b.w);
    *(uint4*)(dst + i * 8) = pk.v;
  }
}

// cyclase: f32 row -> fp8 row (x16) + exact f32 rowsum. Wave per row.
__global__ __launch_bounds__(256)
void cyccvt(const float* __restrict__ cyc, unsigned* __restrict__ cyc8w,
            float* __restrict__ gsum)
{
  const int lane = threadIdx.x & 63, wid = threadIdx.x >> 6;
  const long row = (long)blockIdx.x * 4 + wid;   // 32768 rows
  const float* src = cyc + row * 1280;
  unsigned* dst = cyc8w + row * 320;
  float s = 0.f;
  #pragma unroll
  for (int i = 0; i < 5; i++) {
    const int d = i * 256 + lane * 4;
    const float4 v = *(const float4*)(src + d);
    s += v.x + v.y + v.z + v.w;
    dst[d >> 2] = pack4_fp8(v.x * 16.f, v.y * 16.f, v.z * 16.f, v.w * 16.f);
  }
  #pragma unroll
  for (int o = 1; o < 64; o <<= 1) s += __shfl_xor(s, o);
  if (lane == 0) gsum[row] = s;
}

// substrate fused pass: f32 row read ONCE -> sub8 (fp8 x16) + exact tbar.
__global__ __launch_bounds__(256)
void subprep(const float* __restrict__ sub, const float* __restrict__ mcol,
             unsigned* __restrict__ sub8w, float* __restrict__ tbar)
{
  __shared__ float mc[1280];
  for (int i = threadIdx.x; i < 1280; i += 256) mc[i] = mcol[i];
  __syncthreads();
  const int lane = threadIdx.x & 63, wid = threadIdx.x >> 6;
  const long row = (long)blockIdx.x * 4 + wid;   // 16384 rows
  const float4* sp = (const float4*)(sub + row * 1280);
  unsigned* dp = sub8w + row * 320;
  float d = 0.f;
  #pragma unroll
  for (int i = 0; i < 5; i++) {
    const int c = i * 64 + lane;
    const float4 v = sp[c];
    d += v.x * mc[c * 4] + v.y * mc[c * 4 + 1] + v.z * mc[c * 4 + 2] + v.w * mc[c * 4 + 3];
    dp[c] = pack4_fp8(v.x * 16.f, v.y * 16.f, v.z * 16.f, v.w * 16.f);
  }
  #pragma unroll
  for (int o = 1; o < 64; o <<= 1) d += __shfl_xor(d, o);
  if (lane == 0) tbar[row] = d;
}

// ---------------------------------------------------------------------------
// bf16 GEMM 8-phase (r6 structure, BM=128) — Mkq only (small).
// ---------------------------------------------------------------------------
__global__ __launch_bounds__(512, 4)
void gemm_mkq(const ushort* __restrict__ A, const ushort* __restrict__ B,
              ushort* __restrict__ C, int K, int N, int nbx, float scale)
{
  __shared__ __align__(16) ushort As[4][4][128][8];
  __shared__ __align__(16) ushort Bs[4][4][128][8];
  const int tid = threadIdx.x, lane = tid & 63, wid = tid >> 6;
  const int wr = wid >> 2, wc = wid & 3;
  const int bx = blockIdx.x % nbx, by = blockIdx.x / nbx;
  const int bm = by * 128, bn = bx * 128;

  f32x16 acc[2];
  #pragma unroll
  for (int i = 0; i < 2; i++)
    #pragma unroll
    for (int e = 0; e < 16; e++) acc[i][e] = 0.f;

  const int kbA = wid >> 1, rqA = wid & 1;
  const ushort* agp = A + (long)(bm + rqA * 64 + lane) * K + kbA * 8;
  const ushort* bgp = B + (long)(bn + rqA * 64 + lane) * K + kbA * 8;
  auto STAGE = [&](int g, int rg) {
    gload16(agp + g * 32, &As[rg][kbA][rqA * 64][0]);
    gload16(bgp + g * 32, &Bs[rg][kbA][rqA * 64][0]);
  };
  const int NG = K >> 5;
  STAGE(0, 0); STAGE(1, 1);
  asm volatile("s_waitcnt vmcnt(2)" ::: "memory");
  __builtin_amdgcn_s_barrier();
  const int lkh = lane >> 5, lr = lane & 31;
  auto GROUP = [&](int g, int rg, int rg2) {
    bf16x8 av[2][2], bv[2];
    #pragma unroll
    for (int kf = 0; kf < 2; kf++) {
      #pragma unroll
      for (int mi = 0; mi < 2; mi++)
        av[mi][kf] = *(const bf16x8*)&As[rg][kf * 2 + lkh][wr * 64 + mi * 32 + lr][0];
      bv[kf] = *(const bf16x8*)&Bs[rg][kf * 2 + lkh][wc * 32 + lr][0];
    }
    if (g + 2 < NG) STAGE(g + 2, rg2);
    __builtin_amdgcn_s_barrier();
    __builtin_amdgcn_s_setprio(1);
    #pragma unroll
    for (int mi = 0; mi < 2; mi++)
      #pragma unroll
      for (int kf = 0; kf < 2; kf++)
        acc[mi] = __builtin_amdgcn_mfma_f32_32x32x16_bf16(av[mi][kf], bv[kf], acc[mi], 0, 0, 0);
    __builtin_amdgcn_s_setprio(0);
    if (g + 2 < NG)      asm volatile("s_waitcnt vmcnt(2)" ::: "memory");
    else if (g + 1 < NG) asm volatile("s_waitcnt vmcnt(0)" ::: "memory");
    __builtin_amdgcn_s_barrier();
  };
  for (int g = 0; g < NG; g += 4) {
    GROUP(g, 0, 2); GROUP(g + 1, 1, 3); GROUP(g + 2, 2, 0); GROUP(g + 3, 3, 1);
  }
  #pragma unroll
  for (int mi = 0; mi < 2; mi++)
    #pragma unroll
    for (int rr = 0; rr < 16; rr++) {
      const int row = bm + wr * 64 + mi * 32 + (rr & 3) + 8 * (rr >> 2) + 4 * lkh;
      const int col = bn + wc * 32 + lr;
      C[(long)row * N + col] = f2bf(acc[mi][rr] * scale);
    }
}

// mcol[d] += partial col-mean.  Grid (5, 32).
__global__ __launch_bounds__(256)
void colmean(const ushort* __restrict__ Mkq, float* __restrict__ mcol)
{
  const int d = blockIdx.x * 256 + threadIdx.x;
  const int r0 = blockIdx.y * 40;
  float s = 0.f;
  for (int j = 0; j < 40; j++) s += bf2f(Mkq[(long)(r0 + j) * 1280 + d]);
  atomicAdd(&mcol[d], s * (1.f / 1280.f));
}

// M2_8[j][d] = e4m3((Mkq[j][d] - mcol[d]) * 2^19)
__global__ __launch_bounds__(320)
void m2cvt(const ushort* __restrict__ Mkq, const float* __restrict__ mcol,
           unsigned* __restrict__ M2w)
{
  const int j = blockIdx.x;
  const int d = threadIdx.x * 4;
  const ushort* mr = Mkq + (long)j * 1280 + d;
  const float* mc = mcol + d;
  M2w[j * 320 + threadIdx.x] = pack4_fp8(
      (bf2f(mr[0]) - mc[0]) * 524288.f, (bf2f(mr[1]) - mc[1]) * 524288.f,
      (bf2f(mr[2]) - mc[2]) * 524288.f, (bf2f(mr[3]) - mc[3]) * 524288.f);
}

// ---------------------------------------------------------------------------
// fp8 GEMM 256x256, MX-scaled MFMA K=64 (unit scales): r10 sync skeleton
// (ring-4, depth-2, gload16) with one scaled MFMA per (mi,ni) per group —
// 8 instrs/group vs 32, 2x matrix rate (m148). Frag reads become paired
// ds_read_b128 at 16B row stride -> conflict-free (fixes the 7.86M
// conflicts without touching the staging path).  Lane K-map: k =
// 32*(lane>>5) + 0..31  ==  kf pair {2*lkh, 2*lkh+1} of [kf][row][16].
// MODE 0: C = bf16( acc*2^-16 + tbar[z*1024+row]*gsum[z*2048+col] )   (S)
// ---------------------------------------------------------------------------
template<int MODE, bool BY_FAST>
__global__ __launch_bounds__(512, 2)
void gemm_f8(const unsigned char* __restrict__ A, const unsigned char* __restrict__ B,
             void* __restrict__ Cv, int K, int N, int nbx, int nby,
             long sA, long sB, long sC,
             const float* __restrict__ tbar, const float* __restrict__ gsum)
{
  __shared__ __align__(16) unsigned char As[4][4][256][16];  // 64 KB
  __shared__ __align__(16) unsigned char Bs[4][4][256][16];  // 64 KB
  const int tid = threadIdx.x, lane = tid & 63, wid = tid >> 6;
  const int wr = wid >> 2, wc = wid & 3;

  const int nwg = gridDim.x;
  const int q = nwg >> 3, r = nwg & 7;
  const int xcd = blockIdx.x & 7, lid = blockIdx.x >> 3;
  const int id = (xcd < r ? xcd * (q + 1) : r * (q + 1) + (xcd - r) * q) + lid;
  const int per = nbx * nby;
  const int z = id / per, rem = id - z * per;
  const int bx = BY_FAST ? rem / nby : rem % nbx;
  const int by = BY_FAST ? rem % nby : rem / nbx;
  const int bm = by * 256, bn = bx * 256;
  const long Ab = (long)z * sA, Bb = (long)z * sB, Cb = (long)z * sC;

  f32x16 acc[4][2];
  #pragma unroll
  for (int i = 0; i < 4; i++)
    #pragma unroll
    for (int j = 0; j < 2; j++)
      #pragma unroll
      for (int e = 0; e < 16; e++) acc[i][j][e] = 0.f;

  const int c0 = wid * 2, c1 = wid * 2 + 1;
  const int kb0 = c0 >> 2, rq0 = c0 & 3, kb1 = c1 >> 2, rq1 = c1 & 3;
  const unsigned char* ag0 = A + Ab + (long)(bm + rq0 * 64 + lane) * K + kb0 * 16;
  const unsigned char* ag1 = A + Ab + (long)(bm + rq1 * 64 + lane) * K + kb1 * 16;
  const unsigned char* bg0 = B + Bb + (long)(bn + rq0 * 64 + lane) * K + kb0 * 16;
  const unsigned char* bg1 = B + Bb + (long)(bn + rq1 * 64 + lane) * K + kb1 * 16;
  auto STAGE_A = [&](int g, int rg) {
    gload16(ag0 + g * 64, &As[rg][kb0][rq0 * 64][0]);
    gload16(ag1 + g * 64, &As[rg][kb1][rq1 * 64][0]);
  };
  auto STAGE_B = [&](int g, int rg) {
    gload16(bg0 + g * 64, &Bs[rg][kb0][rq0 * 64][0]);
    gload16(bg1 + g * 64, &Bs[rg][kb1][rq1 * 64][0]);
  };

  const int NG = K >> 6;  // 64-K groups, multiple of 4
  STAGE_A(0, 0); STAGE_B(0, 0); STAGE_A(1, 1); STAGE_B(1, 1);
  asm volatile("s_waitcnt vmcnt(4)" ::: "memory");
  __builtin_amdgcn_s_barrier();

  const int lkh = lane >> 5, lr = lane & 31;
  const int kfb = lkh * 2;   // this lane's 32B k-half = kf pair {kfb, kfb+1}

  auto LDA = [&](int rg, int row) -> i32x8 {
    union { uint4 q[2]; i32x8 v; } u;
    u.q[0] = *(const uint4*)&As[rg][kfb][row][0];
    u.q[1] = *(const uint4*)&As[rg][kfb + 1][row][0];
    return u.v;
  };
  auto LDB = [&](int rg, int row) -> i32x8 {
    union { uint4 q[2]; i32x8 v; } u;
    u.q[0] = *(const uint4*)&Bs[rg][kfb][row][0];
    u.q[1] = *(const uint4*)&Bs[rg][kfb + 1][row][0];
    return u.v;
  };

  auto GROUP = [&](int g, int rg, int rg2) {
    const bool pre = (g + 2 < NG);
    i32x8 av0 = LDA(rg, wr * 128 + lr);
    i32x8 av1 = LDA(rg, wr * 128 + 32 + lr);
    i32x8 bv0 = LDB(rg, wc * 64 + lr);
    i32x8 bv1 = LDB(rg, wc * 64 + 32 + lr);
    if (pre) STAGE_A(g + 2, rg2);
    __builtin_amdgcn_s_barrier();
    __builtin_amdgcn_s_setprio(1);
    acc[0][0] = mfma64(av0, bv0, acc[0][0]);
    acc[0][1] = mfma64(av0, bv1, acc[0][1]);
    acc[1][0] = mfma64(av1, bv0, acc[1][0]);
    acc[1][1] = mfma64(av1, bv1, acc[1][1]);
    __builtin_amdgcn_s_setprio(0);
    __builtin_amdgcn_s_barrier();
    av0 = LDA(rg, wr * 128 + 64 + lr);
    av1 = LDA(rg, wr * 128 + 96 + lr);
    if (pre) STAGE_B(g + 2, rg2);
    __builtin_amdgcn_s_barrier();
    __builtin_amdgcn_s_setprio(1);
    acc[2][0] = mfma64(av0, bv0, acc[2][0]);
    acc[2][1] = mfma64(av0, bv1, acc[2][1]);
    acc[3][0] = mfma64(av1, bv0, acc[3][0]);
    acc[3][1] = mfma64(av1, bv1, acc[3][1]);
    __builtin_amdgcn_s_setprio(0);
    if (pre)             asm volatile("s_waitcnt vmcnt(4)" ::: "memory");
    else if (g + 1 < NG) asm volatile("s_waitcnt vmcnt(0)" ::: "memory");
    __builtin_amdgcn_s_barrier();
  };

  for (int g = 0; g < NG; g += 4) {
    GROUP(g, 0, 2); GROUP(g + 1, 1, 3); GROUP(g + 2, 2, 0); GROUP(g + 3, 3, 1);
  }

  // C/D 32x32: col=lane&31, row=(reg&3)+8*(reg>>2)+4*(lane>>5)
  #pragma unroll
  for (int mi = 0; mi < 4; mi++)
    #pragma unroll
    for (int ni = 0; ni < 2; ni++)
      #pragma unroll
      for (int rr = 0; rr < 16; rr++) {
        const int row = bm + wr * 128 + mi * 32 + (rr & 3) + 8 * (rr >> 2) + 4 * lkh;
        const int col = bn + wc * 64 + ni * 32 + lr;
        if constexpr (MODE == 0) {
          const float v = acc[mi][ni][rr] * 0x1p-16f
                        + tbar[(long)z * 1024 + row] * gsum[(long)z * 2048 + col];
          ((ushort*)Cv)[Cb + (long)row * N + col] = f2bf(v);
        } else {
          ((unsigned char*)Cv)[Cb + (long)row * N + col] = enc_fp8(acc[mi][ni][rr] * 0x1p-11f);
        }
      }
}

// ---------------------------------------------------------------------------
// fp8 GEMM 128x128 (T1'), MX-scaled K=64. 64 KB LDS + 32-reg acc ->
// 2 blocks/CU. Wave tile 64x32. C = e4m3( acc * 2^-11 ).
// ---------------------------------------------------------------------------
__global__ __launch_bounds__(512, 4)
void gemm_f8_128(const unsigned char* __restrict__ A, const unsigned char* __restrict__ B,
                 unsigned char* __restrict__ C, int K, int N, int nbx)
{
  __shared__ __align__(16) unsigned char As[4][4][128][16];  // 32 KB
  __shared__ __align__(16) unsigned char Bs[4][4][128][16];  // 32 KB
  const int tid = threadIdx.x, lane = tid & 63, wid = tid >> 6;
  const int wr = wid >> 2, wc = wid & 3;

  const int nwg = gridDim.x;
  const int q = nwg >> 3, r = nwg & 7;
  const int xcd = blockIdx.x & 7, lid = blockIdx.x >> 3;
  const int id = (xcd < r ? xcd * (q + 1) : r * (q + 1) + (xcd - r) * q) + lid;
  const int bx = id % nbx, by = id / nbx;
  const int bm = by * 128, bn = bx * 128;

  f32x16 acc[2];
  #pragma unroll
  for (int i = 0; i < 2; i++)
    #pragma unroll
    for (int e = 0; e < 16; e++) acc[i][e] = 0.f;

  const int kbA = wid >> 1, rhA = wid & 1;
  const unsigned char* agp = A + (long)(bm + rhA * 64 + lane) * K + kbA * 16;
  const unsigned char* bgp = B + (long)(bn + rhA * 64 + lane) * K + kbA * 16;
  auto STAGE = [&](int g, int rg) {
    gload16(agp + g * 64, &As[rg][kbA][rhA * 64][0]);
    gload16(bgp + g * 64, &Bs[rg][kbA][rhA * 64][0]);
  };
  const int NG = K >> 6;  // K=1280 -> 20
  STAGE(0, 0); STAGE(1, 1);
  asm volatile("s_waitcnt vmcnt(2)" ::: "memory");
  __builtin_amdgcn_s_barrier();

  const int lkh = lane >> 5, lr = lane & 31;
  const int kfb = lkh * 2;

  auto LDA = [&](int rg, int row) -> i32x8 {
    union { uint4 q[2]; i32x8 v; } u;
    u.q[0] = *(const uint4*)&As[rg][kfb][row][0];
    u.q[1] = *(const uint4*)&As[rg][kfb + 1][row][0];
    return u.v;
  };
  auto LDB = [&](int rg, int row) -> i32x8 {
    union { uint4 q[2]; i32x8 v; } u;
    u.q[0] = *(const uint4*)&Bs[rg][kfb][row][0];
    u.q[1] = *(const uint4*)&Bs[rg][kfb + 1][row][0];
    return u.v;
  };

  auto GROUP = [&](int g, int rg, int rg2) {
    i32x8 av0 = LDA(rg, wr * 64 + lr);
    i32x8 av1 = LDA(rg, wr * 64 + 32 + lr);
    i32x8 bv  = LDB(rg, wc * 32 + lr);
    if (g + 2 < NG) STAGE(g + 2, rg2);
    __builtin_amdgcn_s_barrier();
    __builtin_amdgcn_s_setprio(1);
    acc[0] = mfma64(av0, bv, acc[0]);
    acc[1] = mfma64(av1, bv, acc[1]);
    __builtin_amdgcn_s_setprio(0);
    if (g + 2 < NG)      asm volatile("s_waitcnt vmcnt(2)" ::: "memory");
    else if (g + 1 < NG) asm volatile("s_waitcnt vmcnt(0)" ::: "memory");
    __builtin_amdgcn_s_barrier();
  };
  for (int g = 0; g < NG; g += 4) {
    GROUP(g, 0, 2); GROUP(g + 1, 1, 3); GROUP(g + 2, 2, 0); GROUP(g + 3, 3, 1);
  }

  #pragma unroll
  for (int mi = 0; mi < 2; mi++)
    #pragma unroll
    for (int rr = 0; rr < 16; rr++) {
      const int row = bm + wr * 64 + mi * 32 + (rr & 3) + 8 * (rr >> 2) + 4 * lkh;
      const int col = bn + wc * 32 + lr;
      C[(long)row * N + col] = enc_fp8(acc[mi][rr] * 0x1p-11f);
    }
}

// ---------------------------------------------------------------------------
// Softmax over c per (b,s) row of S (bf16); wsum[b,c] += softmax row.
// ---------------------------------------------------------------------------
__global__ __launch_bounds__(256)
void softmax_wsum(const ushort* __restrict__ S, float* __restrict__ wsum)
{
  const int b = blockIdx.x;
  const int s0 = blockIdx.y * 32;
  const int lane = threadIdx.x & 63;
  const int w = threadIdx.x >> 6;
  __shared__ float red[4][2048];
  const ushort* Sb = S + (((long)b * 1024) + s0 + w * 8) * 2048;

  float acc[32];
  #pragma unroll
  for (int i = 0; i < 32; i++) acc[i] = 0.f;
  for (int r = 0; r < 8; r++) {
    const ushort* row = Sb + (long)r * 2048;
    float v[32];
    #pragma unroll
    for (int i = 0; i < 4; i++) {
      uint4 u = *(const uint4*)(row + i * 512 + lane * 8);
      const ushort* up = (const ushort*)&u;
      #pragma unroll
      for (int j = 0; j < 8; j++) v[i * 8 + j] = bf2f(up[j]);
    }
    float m = v[0];
    #pragma unroll
    for (int i = 1; i < 32; i++) m = fmaxf(m, v[i]);
    #pragma unroll
    for (int o = 1; o < 64; o <<= 1) m = fmaxf(m, __shfl_xor(m, o));
    float ssum = 0.f;
    #pragma unroll
    for (int i = 0; i < 32; i++) { v[i] = __expf(v[i] - m); ssum += v[i]; }
    #pragma unroll
    for (int o = 1; o < 64; o <<= 1) ssum += __shfl_xor(ssum, o);
    const float inv = 1.f / ssum;
    #pragma unroll
    for (int i = 0; i < 32; i++) acc[i] += v[i] * inv;
  }
  #pragma unroll
  for (int i = 0; i < 4; i++)
    #pragma unroll
    for (int j = 0; j < 8; j++)
      red[w][i * 512 + lane * 8 + j] = acc[i * 8 + j];
  __syncthreads();
  float* wb = wsum + b * 2048;
  #pragma unroll
  for (int k = 0; k < 8; k++) {
    const int c = k * 256 + threadIdx.x;
    atomicAdd(&wb[c], red[0][c] + red[1][c] + red[2][c] + red[3][c]);
  }
}

// t[b,d] = sum_c wsum[b,c] * cyc8[b,c,d]/16
__global__ __launch_bounds__(320)
void wcyc_kernel(const unsigned char* __restrict__ cyc8, const float* __restrict__ wsum,
                 float* __restrict__ t)
{
  const int b = blockIdx.x;
  const int c0 = blockIdx.y * 64;
  const int d = threadIdx.x * 4;
  const unsigned char* cb = cyc8 + ((long)b * 2048 + c0) * 1280 + d;
  const float* wb = wsum + b * 2048 + c0;
  float4 a = {0.f, 0.f, 0.f, 0.f};
  for (int c = 0; c < 64; c++) {
    const unsigned u = *(const unsigned*)(cb + (long)c * 1280);
    const float w = wb[c];
    a.x += w * dec_fp8<0>(u); a.y += w * dec_fp8<1>(u);
    a.z += w * dec_fp8<2>(u); a.w += w * dec_fp8<3>(u);
  }
  atomicAdd(&t[b * 1280 + d + 0], a.x * 0.0625f);
  atomicAdd(&t[b * 1280 + d + 1], a.y * 0.0625f);
  atomicAdd(&t[b * 1280 + d + 2], a.z * 0.0625f);
  atomicAdd(&t[b * 1280 + d + 3], a.w * 0.0625f);
}

// xcat[b, 1280+d] += partial mean over 64-s chunk (grid 16x16 — was the
// 64-block latency elephant candidate).
__global__ __launch_bounds__(320)
void submean8(const unsigned char* __restrict__ sub8, float* __restrict__ xcat)
{
  const int b = blockIdx.x;
  const int s0 = blockIdx.y * 64;
  const int d = threadIdx.x * 4;
  const unsigned char* sp = sub8 + ((long)b * 1024 + s0) * 1280 + d;
  float4 a = {0.f, 0.f, 0.f, 0.f};
  for (int s = 0; s < 64; s++) {
    const unsigned u = *(const unsigned*)(sp + (long)s * 1280);
    a.x += dec_fp8<0>(u); a.y += dec_fp8<1>(u);
    a.z += dec_fp8<2>(u); a.w += dec_fp8<3>(u);
  }
  const float k = 1.f / (16.f * 1024.f);
  atomicAdd(&xcat[b * 2560 + 1280 + d + 0], a.x * k);
  atomicAdd(&xcat[b * 2560 + 1280 + d + 1], a.y * k);
  atomicAdd(&xcat[b * 2560 + 1280 + d + 2], a.z * k);
  atomicAdd(&xcat[b * 2560 + 1280 + d + 3], a.w * k);
}

// xcat[b, dp] += (1/1024) * sum_{d in 256-chunk} t[b,d] * Wv[d,dp]
// grid (5, 16, 5): d-split kills the 80-block serial-1280 latency chain.
__global__ __launch_bounds__(256)
void xv_kernel(const float* __restrict__ t, const float* __restrict__ Wv,
               float* __restrict__ xcat)
{
  const int b = blockIdx.y;
  const int dp = blockIdx.x * 256 + threadIdx.x;
  const int d0 = blockIdx.z * 256;
  __shared__ float tl[256];
  tl[threadIdx.x] = t[b * 1280 + d0 + threadIdx.x];
  __syncthreads();
  float a = 0.f;
  for (int d = 0; d < 256; d++) a += tl[d] * Wv[(long)(d0 + d) * 1280 + dp];
  atomicAdd(&xcat[b * 2560 + dp], a * (1.f / 1024.f));
}

// h1pre[b,j] += sum_{d in 320-chunk} xcat[b,d] * W1[d,j]   grid (2,16,8)
__global__ __launch_bounds__(256)
void mlp1_partial(const float* __restrict__ xcat, const float* __restrict__ W1,
                  float* __restrict__ h1pre)
{
  const int b = blockIdx.y;
  const int j = blockIdx.x * 256 + threadIdx.x;
  const int d0 = blockIdx.z * 320;
  __shared__ float xl[320];
  for (int i = threadIdx.x; i < 320; i += 256) xl[i] = xcat[b * 2560 + d0 + i];
  __syncthreads();
  float a = 0.f;
  for (int d = 0; d < 320; d++) a += xl[d] * W1[(long)(d0 + d) * 512 + j];
  atomicAdd(&h1pre[b * 512 + j], a);
}

// h = relu(h1pre + b1); h2 = relu(h @ W2 + b2); out = sigmoid(h2 @ W3 + b3)
__global__ __launch_bounds__(64)
void mlp23_kernel(const float* __restrict__ h1pre, const float* __restrict__ b1,
                  const float* __restrict__ W2, const float* __restrict__ b2,
                  const float* __restrict__ W3, const float* __restrict__ b3,
                  float* __restrict__ out)
{
  const int b = blockIdx.x;
  const int j = threadIdx.x;
  __shared__ float hl[512];
  for (int i = j; i < 512; i += 64) hl[i] = fmaxf(h1pre[b * 512 + i] + b1[i], 0.f);
  __syncthreads();
  float a = b2[j];
  for (int d = 0; d < 512; d++) a += hl[d] * W2[d * 64 + j];
  a = fmaxf(a, 0.f);
  float p = a * W3[j];
  #pragma unroll
  for (int o = 1; o < 64; o <<= 1) p += __shfl_xor(p, o);
  if (j == 0) out[b] = 1.f / (1.f + __expf(-(p + b3[0])));
}

extern "C" void kernel_launch(void* const* d_in, const int* in_sizes, int n_in,
                              void* d_out, int out_size, void* d_ws, size_t ws_size,
                              hipStream_t stream)
{
  const float* cyclase   = (const float*)d_in[0];
  const float* substrate = (const float*)d_in[1];
  const float* Wq = (const float*)d_in[4];
  const float* Wk = (const float*)d_in[5];
  const float* Wv = (const float*)d_in[6];
  const float* W1 = (const float*)d_in[7];
  const float* b1 = (const float*)d_in[8];
  const float* W2 = (const float*)d_in[9];
  const float* b2 = (const float*)d_in[10];
  const float* W3 = (const float*)d_in[11];
  const float* b3 = (const float*)d_in[12];
  float* out = (float*)d_out;
  (void)in_sizes; (void)n_in; (void)out_size; (void)ws_size;

  char* ws = (char*)d_ws;
  unsigned char* cyc8 = (unsigned char*)ws;
  char* A2 = ws + 41943040;
  ushort* Mkq   = (ushort*)(A2 + 41943040);
  ushort* Wq16  = (ushort*)(A2 + 41943040 + 3276800);
  ushort* Wk16  = (ushort*)(A2 + 41943040 + 2 * 3276800);
  unsigned char* sub8 = (unsigned char*)(A2 + 41943040 + 3 * 3276800);
  ushort* S = (ushort*)A2;                       // overlays region2
  char* B2 = A2 + 41943040 + 3 * 3276800 + 20971520;
  unsigned char* T1p8 = (unsigned char*)B2;
  unsigned char* M2_8 = (unsigned char*)(B2 + 20971520);
  char* C2 = B2 + 20971520 + 1638400;
  float* mcol  = (float*)C2;
  float* tbar  = (float*)(C2 + 8192);
  float* gsum  = (float*)(C2 + 8192 + 65536);
  float* wsum  = (float*)(C2 + 8192 + 65536 + 131072);
  float* tbuf  = (float*)(C2 + 8192 + 65536 + 2 * 131072);
  float* xcat  = (float*)(C2 + 8192 + 65536 + 2 * 131072 + 81920);
  float* h1pre = (float*)(C2 + 8192 + 65536 + 2 * 131072 + 81920 + 163840);

  hipMemsetAsync(mcol, 0, 1280 * 4, stream);
  hipMemsetAsync(wsum, 0, 16 * 2048 * 4, stream);
  hipMemsetAsync(tbuf, 0, 16 * 1280 * 4, stream);
  hipMemsetAsync(xcat, 0, 16 * 2560 * 4, stream);
  hipMemsetAsync(h1pre, 0, 16 * 512 * 4, stream);

  cvt_bf16<<<200, 256, 0, stream>>>(Wq, Wq16, 1280l * 1280 / 8);
  cvt_bf16<<<200, 256, 0, stream>>>(Wk, Wk16, 1280l * 1280 / 8);
  cyccvt<<<8192, 256, 0, stream>>>(cyclase, (unsigned*)cyc8, gsum);

  // Mkq = Wk @ Wq^T * (1/sqrt(1280))  [1280,1280] bf16
  gemm_mkq<<<100, 512, 0, stream>>>(Wk16, Wq16, Mkq, 1280, 1280, 10,
                                    0.02795084971874737f);
  colmean<<<dim3(5, 32), 256, 0, stream>>>(Mkq, mcol);
  m2cvt<<<1280, 320, 0, stream>>>(Mkq, mcol, (unsigned*)M2_8);

  // fused substrate pass: sub8 + exact tbar in one 84 MB read
  subprep<<<4096, 256, 0, stream>>>(substrate, mcol, (unsigned*)sub8, tbar);
  submean8<<<dim3(16, 16), 320, 0, stream>>>(sub8, xcat);

  // T1' = sub8 @ M2_8^T -> fp8 x4096   [16384,1280]
  gemm_f8_128<<<1280, 512, 0, stream>>>(sub8, M2_8, T1p8, 1280, 1280, 10);

  // S[b] = T1'8 @ cyc8^T * 2^-16 + tbar x gsum -> bf16  [16,1024,2048]
  gemm_f8<0, true><<<512, 512, 0, stream>>>(T1p8, cyc8, S,
      1280, 2048, 8, 4, 1024l * 1280, 2048l * 1280, 1024l * 2048, tbar, gsum);

  softmax_wsum<<<dim3(16, 32), 256, 0, stream>>>(S, wsum);
  wcyc_kernel<<<dim3(16, 32), 320, 0, stream>>>(cyc8, wsum, tbuf);
  xv_kernel<<<dim3(5, 16, 5), 256, 0, stream>>>(tbuf, Wv, xcat);
  mlp1_partial<<<dim3(2, 16, 8), 256, 0, stream>>>(xcat, W1, h1pre);
  mlp23_kernel<<<16, 64, 0, stream>>>(h1pre, b1, W2, b2, W3, b3, out);
}

// Round 16
// 391.941 us; speedup vs baseline: 1.6731x; 1.6731x over previous
//
#include <hip/hip_runtime.h>
#include <hip/hip_bf16.h>

#define DEV static __device__ __forceinline__

typedef __attribute__((ext_vector_type(16))) float f32x16;
typedef __attribute__((ext_vector_type(8)))  short bf16x8;

#if defined(__has_builtin)
#  if __has_builtin(__builtin_amdgcn_cvt_pk_fp8_f32) && __has_builtin(__builtin_amdgcn_cvt_f32_fp8)
#    define HW_FP8 1
#  endif
#endif

DEV ushort f2bf(float f){
  union { float f; unsigned u; } v; v.f = f;
  return (ushort)((v.u + 0x7FFFu + ((v.u >> 16) & 1u)) >> 16);
}
DEV float bf2f(ushort u){
  union { unsigned u; float f; } v; v.u = ((unsigned)u) << 16;
  return v.f;
}

DEV unsigned char f2e4m3_sw(float f){
  union { float f; unsigned u; } v; v.f = f;
  unsigned s = (v.u >> 24) & 0x80;
  float a = fabsf(f);
  if (a >= 448.f) return s | 0x7E;
  if (a < 0.0009765625f) return (unsigned char)s;
  if (a < 0.015625f) {
    int m = (int)rintf(a * 512.f);
    return (unsigned char)(s | (m >= 8 ? 8 : m));
  }
  unsigned ab = v.u & 0x7FFFFFFF;
  unsigned r = ab + 0x0007FFFF + ((ab >> 20) & 1);
  unsigned e = (r >> 23) - 127 + 7;
  unsigned m = (r >> 20) & 7;
  if (e > 15 || (e == 15 && m > 6)) return s | 0x7E;
  return (unsigned char)(s | (e << 3) | m);
}
DEV float e4m32f_sw(unsigned char c){
  unsigned e = (c >> 3) & 15, m = c & 7;
  float v;
  if (e) { union { unsigned u; float f; } w; w.u = ((e + 120u) << 23) | (m << 20); v = w.f; }
  else v = (float)m * 0.001953125f;
  return (c & 0x80) ? -v : v;
}

DEV unsigned pack4_fp8(float a, float b, float c, float d){
#ifdef HW_FP8
  int v = __builtin_amdgcn_cvt_pk_fp8_f32(a, b, 0, false);
  v = __builtin_amdgcn_cvt_pk_fp8_f32(c, d, v, true);
  return (unsigned)v;
#else
  return (unsigned)f2e4m3_sw(a) | ((unsigned)f2e4m3_sw(b) << 8)
       | ((unsigned)f2e4m3_sw(c) << 16) | ((unsigned)f2e4m3_sw(d) << 24);
#endif
}
DEV unsigned char enc_fp8(float a){
#ifdef HW_FP8
  return (unsigned char)(__builtin_amdgcn_cvt_pk_fp8_f32(a, a, 0, false) & 0xFF);
#else
  return f2e4m3_sw(a);
#endif
}
template<int SEL>
DEV float dec_fp8(unsigned u){
#ifdef HW_FP8
  return __builtin_amdgcn_cvt_f32_fp8((int)u, SEL);
#else
  return e4m32f_sw((u >> (SEL * 8)) & 0xFF);
#endif
}

// async global->LDS, 16B per lane; LDS dest is wave-uniform base + lane*16.
DEV void gload16(const void* g, void* l) {
  __builtin_amdgcn_global_load_lds(
      (const __attribute__((address_space(1))) unsigned*)g,
      (__attribute__((address_space(3))) unsigned*)l, 16, 0, 0);
}

// ---------------------------------------------------------------------------
// Elementwise f32 -> bf16 (Wq/Wk only).
// ---------------------------------------------------------------------------
__global__ __launch_bounds__(256)
void cvt_bf16(const float* __restrict__ src, ushort* __restrict__ dst, long n8)
{
  const long stride = (long)gridDim.x * 256;
  for (long i = (long)blockIdx.x * 256 + threadIdx.x; i < n8; i += stride) {
    const float4 a = *(const float4*)(src + i * 8);
    const float4 b = *(const float4*)(src + i * 8 + 4);
    union { ushort u[8]; uint4 v; } pk;
    pk.u[0] = f2bf(a.x); pk.u[1] = f2bf(a.y); pk.u[2] = f2bf(a.z); pk.u[3] = f2bf(a.w);
    pk.u[4] = f2bf(b.x); pk.u[5] = f2bf(b.y); pk.u[6] = f2bf(b.z); pk.u[7] = f2bf(b.w);
    *(uint4*)(dst + i * 8) = pk.v;
  }
}

// cyclase: f32 row -> fp8 row (x16) + exact f32 rowsum. Wave per row.
__global__ __launch_bounds__(256)
void cyccvt(const float* __restrict__ cyc, unsigned* __restrict__ cyc8w,
            float* __restrict__ gsum)
{
  const int lane = threadIdx.x & 63, wid = threadIdx.x >> 6;
  const long row = (long)blockIdx.x * 4 + wid;   // 32768 rows
  const float* src = cyc + row * 1280;
  unsigned* dst = cyc8w + row * 320;
  float s = 0.f;
  #pragma unroll
  for (int i = 0; i < 5; i++) {
    const int d = i * 256 + lane * 4;
    const float4 v = *(const float4*)(src + d);
    s += v.x + v.y + v.z + v.w;
    dst[d >> 2] = pack4_fp8(v.x * 16.f, v.y * 16.f, v.z * 16.f, v.w * 16.f);
  }
  #pragma unroll
  for (int o = 1; o < 64; o <<= 1) s += __shfl_xor(s, o);
  if (lane == 0) gsum[row] = s;
}

// substrate fused pass: f32 row read ONCE -> sub8 (fp8 x16) + exact tbar.
__global__ __launch_bounds__(256)
void subprep(const float* __restrict__ sub, const float* __restrict__ mcol,
             unsigned* __restrict__ sub8w, float* __restrict__ tbar)
{
  __shared__ float mc[1280];
  for (int i = threadIdx.x; i < 1280; i += 256) mc[i] = mcol[i];
  __syncthreads();
  const int lane = threadIdx.x & 63, wid = threadIdx.x >> 6;
  const long row = (long)blockIdx.x * 4 + wid;   // 16384 rows
  const float4* sp = (const float4*)(sub + row * 1280);
  unsigned* dp = sub8w + row * 320;
  float d = 0.f;
  #pragma unroll
  for (int i = 0; i < 5; i++) {
    const int c = i * 64 + lane;
    const float4 v = sp[c];
    d += v.x * mc[c * 4] + v.y * mc[c * 4 + 1] + v.z * mc[c * 4 + 2] + v.w * mc[c * 4 + 3];
    dp[c] = pack4_fp8(v.x * 16.f, v.y * 16.f, v.z * 16.f, v.w * 16.f);
  }
  #pragma unroll
  for (int o = 1; o < 64; o <<= 1) d += __shfl_xor(d, o);
  if (lane == 0) tbar[row] = d;
}

// ---------------------------------------------------------------------------
// bf16 GEMM 8-phase (r6 structure, BM=128) — Mkq only (small).
// ---------------------------------------------------------------------------
__global__ __launch_bounds__(512, 4)
void gemm_mkq(const ushort* __restrict__ A, const ushort* __restrict__ B,
              ushort* __restrict__ C, int K, int N, int nbx, float scale)
{
  __shared__ __align__(16) ushort As[4][4][128][8];
  __shared__ __align__(16) ushort Bs[4][4][128][8];
  const int tid = threadIdx.x, lane = tid & 63, wid = tid >> 6;
  const int wr = wid >> 2, wc = wid & 3;
  const int bx = blockIdx.x % nbx, by = blockIdx.x / nbx;
  const int bm = by * 128, bn = bx * 128;

  f32x16 acc[2];
  #pragma unroll
  for (int i = 0; i < 2; i++)
    #pragma unroll
    for (int e = 0; e < 16; e++) acc[i][e] = 0.f;

  const int kbA = wid >> 1, rqA = wid & 1;
  const ushort* agp = A + (long)(bm + rqA * 64 + lane) * K + kbA * 8;
  const ushort* bgp = B + (long)(bn + rqA * 64 + lane) * K + kbA * 8;
  auto STAGE = [&](int g, int rg) {
    gload16(agp + g * 32, &As[rg][kbA][rqA * 64][0]);
    gload16(bgp + g * 32, &Bs[rg][kbA][rqA * 64][0]);
  };
  const int NG = K >> 5;
  STAGE(0, 0); STAGE(1, 1);
  asm volatile("s_waitcnt vmcnt(2)" ::: "memory");
  __builtin_amdgcn_s_barrier();
  const int lkh = lane >> 5, lr = lane & 31;
  auto GROUP = [&](int g, int rg, int rg2) {
    bf16x8 av[2][2], bv[2];
    #pragma unroll
    for (int kf = 0; kf < 2; kf++) {
      #pragma unroll
      for (int mi = 0; mi < 2; mi++)
        av[mi][kf] = *(const bf16x8*)&As[rg][kf * 2 + lkh][wr * 64 + mi * 32 + lr][0];
      bv[kf] = *(const bf16x8*)&Bs[rg][kf * 2 + lkh][wc * 32 + lr][0];
    }
    if (g + 2 < NG) STAGE(g + 2, rg2);
    __builtin_amdgcn_s_barrier();
    __builtin_amdgcn_s_setprio(1);
    #pragma unroll
    for (int mi = 0; mi < 2; mi++)
      #pragma unroll
      for (int kf = 0; kf < 2; kf++)
        acc[mi] = __builtin_amdgcn_mfma_f32_32x32x16_bf16(av[mi][kf], bv[kf], acc[mi], 0, 0, 0);
    __builtin_amdgcn_s_setprio(0);
    if (g + 2 < NG)      asm volatile("s_waitcnt vmcnt(2)" ::: "memory");
    else if (g + 1 < NG) asm volatile("s_waitcnt vmcnt(0)" ::: "memory");
    __builtin_amdgcn_s_barrier();
  };
  for (int g = 0; g < NG; g += 4) {
    GROUP(g, 0, 2); GROUP(g + 1, 1, 3); GROUP(g + 2, 2, 0); GROUP(g + 3, 3, 1);
  }
  #pragma unroll
  for (int mi = 0; mi < 2; mi++)
    #pragma unroll
    for (int rr = 0; rr < 16; rr++) {
      const int row = bm + wr * 64 + mi * 32 + (rr & 3) + 8 * (rr >> 2) + 4 * lkh;
      const int col = bn + wc * 32 + lr;
      C[(long)row * N + col] = f2bf(acc[mi][rr] * scale);
    }
}

// mcol[d] += partial col-mean.  Grid (5, 32).
__global__ __launch_bounds__(256)
void colmean(const ushort* __restrict__ Mkq, float* __restrict__ mcol)
{
  const int d = blockIdx.x * 256 + threadIdx.x;
  const int r0 = blockIdx.y * 40;
  float s = 0.f;
  for (int j = 0; j < 40; j++) s += bf2f(Mkq[(long)(r0 + j) * 1280 + d]);
  atomicAdd(&mcol[d], s * (1.f / 1280.f));
}

// M2_8[j][d] = e4m3((Mkq[j][d] - mcol[d]) * 2^19)
__global__ __launch_bounds__(320)
void m2cvt(const ushort* __restrict__ Mkq, const float* __restrict__ mcol,
           unsigned* __restrict__ M2w)
{
  const int j = blockIdx.x;
  const int d = threadIdx.x * 4;
  const ushort* mr = Mkq + (long)j * 1280 + d;
  const float* mc = mcol + d;
  M2w[j * 320 + threadIdx.x] = pack4_fp8(
      (bf2f(mr[0]) - mc[0]) * 524288.f, (bf2f(mr[1]) - mc[1]) * 524288.f,
      (bf2f(mr[2]) - mc[2]) * 524288.f, (bf2f(mr[3]) - mc[3]) * 524288.f);
}

// ---------------------------------------------------------------------------
// fp8 GEMM 256x256 (r10/r14 config — best measured): ring-4, depth-2,
// gload16, MFMA 32x32x16_fp8_fp8.
// MODE 0: C = bf16( acc*2^-16 + tbar[z*1024+row]*gsum[z*2048+col] )   (S)
// ---------------------------------------------------------------------------
template<int MODE, bool BY_FAST>
__global__ __launch_bounds__(512, 2)
void gemm_f8(const unsigned char* __restrict__ A, const unsigned char* __restrict__ B,
             void* __restrict__ Cv, int K, int N, int nbx, int nby,
             long sA, long sB, long sC,
             const float* __restrict__ tbar, const float* __restrict__ gsum)
{
  __shared__ __align__(16) unsigned char As[4][4][256][16];  // 64 KB
  __shared__ __align__(16) unsigned char Bs[4][4][256][16];  // 64 KB
  const int tid = threadIdx.x, lane = tid & 63, wid = tid >> 6;
  const int wr = wid >> 2, wc = wid & 3;

  const int nwg = gridDim.x;
  const int q = nwg >> 3, r = nwg & 7;
  const int xcd = blockIdx.x & 7, lid = blockIdx.x >> 3;
  const int id = (xcd < r ? xcd * (q + 1) : r * (q + 1) + (xcd - r) * q) + lid;
  const int per = nbx * nby;
  const int z = id / per, rem = id - z * per;
  const int bx = BY_FAST ? rem / nby : rem % nbx;
  const int by = BY_FAST ? rem % nby : rem / nbx;
  const int bm = by * 256, bn = bx * 256;
  const long Ab = (long)z * sA, Bb = (long)z * sB, Cb = (long)z * sC;

  f32x16 acc[4][2];
  #pragma unroll
  for (int i = 0; i < 4; i++)
    #pragma unroll
    for (int j = 0; j < 2; j++)
      #pragma unroll
      for (int e = 0; e < 16; e++) acc[i][j][e] = 0.f;

  const int c0 = wid * 2, c1 = wid * 2 + 1;
  const int kb0 = c0 >> 2, rq0 = c0 & 3, kb1 = c1 >> 2, rq1 = c1 & 3;
  const unsigned char* ag0 = A + Ab + (long)(bm + rq0 * 64 + lane) * K + kb0 * 16;
  const unsigned char* ag1 = A + Ab + (long)(bm + rq1 * 64 + lane) * K + kb1 * 16;
  const unsigned char* bg0 = B + Bb + (long)(bn + rq0 * 64 + lane) * K + kb0 * 16;
  const unsigned char* bg1 = B + Bb + (long)(bn + rq1 * 64 + lane) * K + kb1 * 16;
  auto STAGE_A = [&](int g, int rg) {
    gload16(ag0 + g * 64, &As[rg][kb0][rq0 * 64][0]);
    gload16(ag1 + g * 64, &As[rg][kb1][rq1 * 64][0]);
  };
  auto STAGE_B = [&](int g, int rg) {
    gload16(bg0 + g * 64, &Bs[rg][kb0][rq0 * 64][0]);
    gload16(bg1 + g * 64, &Bs[rg][kb1][rq1 * 64][0]);
  };

  const int NG = K >> 6;  // 64-K groups, multiple of 4
  STAGE_A(0, 0); STAGE_B(0, 0); STAGE_A(1, 1); STAGE_B(1, 1);
  asm volatile("s_waitcnt vmcnt(4)" ::: "memory");
  __builtin_amdgcn_s_barrier();

  const int lkh = lane >> 5, lr = lane & 31;

  auto GROUP = [&](int g, int rg, int rg2) {
    const bool pre = (g + 2 < NG);
    long av[2][4], bv[2][4];
    #pragma unroll
    for (int kf = 0; kf < 4; kf++) {
      #pragma unroll
      for (int mi = 0; mi < 2; mi++)
        av[mi][kf] = *(const long*)&As[rg][kf][wr * 128 + mi * 32 + lr][lkh * 8];
      #pragma unroll
      for (int ni = 0; ni < 2; ni++)
        bv[ni][kf] = *(const long*)&Bs[rg][kf][wc * 64 + ni * 32 + lr][lkh * 8];
    }
    if (pre) STAGE_A(g + 2, rg2);
    __builtin_amdgcn_s_barrier();
    __builtin_amdgcn_s_setprio(1);
    #pragma unroll
    for (int kf = 0; kf < 4; kf++)
      #pragma unroll
      for (int mi = 0; mi < 2; mi++)
        #pragma unroll
        for (int ni = 0; ni < 2; ni++)
          acc[mi][ni] = __builtin_amdgcn_mfma_f32_32x32x16_fp8_fp8(av[mi][kf], bv[ni][kf], acc[mi][ni], 0, 0, 0);
    __builtin_amdgcn_s_setprio(0);
    __builtin_amdgcn_s_barrier();
    #pragma unroll
    for (int kf = 0; kf < 4; kf++)
      #pragma unroll
      for (int mi = 0; mi < 2; mi++)
        av[mi][kf] = *(const long*)&As[rg][kf][wr * 128 + (mi + 2) * 32 + lr][lkh * 8];
    if (pre) STAGE_B(g + 2, rg2);
    __builtin_amdgcn_s_barrier();
    __builtin_amdgcn_s_setprio(1);
    #pragma unroll
    for (int kf = 0; kf < 4; kf++)
      #pragma unroll
      for (int mi = 0; mi < 2; mi++)
        #pragma unroll
        for (int ni = 0; ni < 2; ni++)
          acc[mi + 2][ni] = __builtin_amdgcn_mfma_f32_32x32x16_fp8_fp8(av[mi][kf], bv[ni][kf], acc[mi + 2][ni], 0, 0, 0);
    __builtin_amdgcn_s_setprio(0);
    if (pre)             asm volatile("s_waitcnt vmcnt(4)" ::: "memory");
    else if (g + 1 < NG) asm volatile("s_waitcnt vmcnt(0)" ::: "memory");
    __builtin_amdgcn_s_barrier();
  };

  for (int g = 0; g < NG; g += 4) {
    GROUP(g, 0, 2); GROUP(g + 1, 1, 3); GROUP(g + 2, 2, 0); GROUP(g + 3, 3, 1);
  }

  // C/D 32x32: col=lane&31, row=(reg&3)+8*(reg>>2)+4*(lane>>5)
  #pragma unroll
  for (int mi = 0; mi < 4; mi++)
    #pragma unroll
    for (int ni = 0; ni < 2; ni++)
      #pragma unroll
      for (int rr = 0; rr < 16; rr++) {
        const int row = bm + wr * 128 + mi * 32 + (rr & 3) + 8 * (rr >> 2) + 4 * lkh;
        const int col = bn + wc * 64 + ni * 32 + lr;
        if constexpr (MODE == 0) {
          const float v = acc[mi][ni][rr] * 0x1p-16f
                        + tbar[(long)z * 1024 + row] * gsum[(long)z * 2048 + col];
          ((ushort*)Cv)[Cb + (long)row * N + col] = f2bf(v);
        } else {
          ((unsigned char*)Cv)[Cb + (long)row * N + col] = enc_fp8(acc[mi][ni][rr] * 0x1p-11f);
        }
      }
}

// ---------------------------------------------------------------------------
// fp8 GEMM 128x128 (T1', r14 config): 2 blocks/CU, 1280 blocks = 5 rounds.
// C = e4m3( acc * 2^-11 ).
// ---------------------------------------------------------------------------
__global__ __launch_bounds__(512, 4)
void gemm_f8_128(const unsigned char* __restrict__ A, const unsigned char* __restrict__ B,
                 unsigned char* __restrict__ C, int K, int N, int nbx)
{
  __shared__ __align__(16) unsigned char As[4][4][128][16];  // 32 KB
  __shared__ __align__(16) unsigned char Bs[4][4][128][16];  // 32 KB
  const int tid = threadIdx.x, lane = tid & 63, wid = tid >> 6;
  const int wr = wid >> 2, wc = wid & 3;

  const int nwg = gridDim.x;
  const int q = nwg >> 3, r = nwg & 7;
  const int xcd = blockIdx.x & 7, lid = blockIdx.x >> 3;
  const int id = (xcd < r ? xcd * (q + 1) : r * (q + 1) + (xcd - r) * q) + lid;
  const int bx = id % nbx, by = id / nbx;
  const int bm = by * 128, bn = bx * 128;

  f32x16 acc[2];
  #pragma unroll
  for (int i = 0; i < 2; i++)
    #pragma unroll
    for (int e = 0; e < 16; e++) acc[i][e] = 0.f;

  const int kbA = wid >> 1, rhA = wid & 1;
  const unsigned char* agp = A + (long)(bm + rhA * 64 + lane) * K + kbA * 16;
  const unsigned char* bgp = B + (long)(bn + rhA * 64 + lane) * K + kbA * 16;
  auto STAGE = [&](int g, int rg) {
    gload16(agp + g * 64, &As[rg][kbA][rhA * 64][0]);
    gload16(bgp + g * 64, &Bs[rg][kbA][rhA * 64][0]);
  };
  const int NG = K >> 6;  // K=1280 -> 20
  STAGE(0, 0); STAGE(1, 1);
  asm volatile("s_waitcnt vmcnt(2)" ::: "memory");
  __builtin_amdgcn_s_barrier();

  const int lkh = lane >> 5, lr = lane & 31;

  auto GROUP = [&](int g, int rg, int rg2) {
    long av[2][4], bv[4];
    #pragma unroll
    for (int kf = 0; kf < 4; kf++) {
      #pragma unroll
      for (int mi = 0; mi < 2; mi++)
        av[mi][kf] = *(const long*)&As[rg][kf][wr * 64 + mi * 32 + lr][lkh * 8];
      bv[kf] = *(const long*)&Bs[rg][kf][wc * 32 + lr][lkh * 8];
    }
    if (g + 2 < NG) STAGE(g + 2, rg2);
    __builtin_amdgcn_s_barrier();
    __builtin_amdgcn_s_setprio(1);
    #pragma unroll
    for (int kf = 0; kf < 4; kf++)
      #pragma unroll
      for (int mi = 0; mi < 2; mi++)
        acc[mi] = __builtin_amdgcn_mfma_f32_32x32x16_fp8_fp8(av[mi][kf], bv[kf], acc[mi], 0, 0, 0);
    __builtin_amdgcn_s_setprio(0);
    if (g + 2 < NG)      asm volatile("s_waitcnt vmcnt(2)" ::: "memory");
    else if (g + 1 < NG) asm volatile("s_waitcnt vmcnt(0)" ::: "memory");
    __builtin_amdgcn_s_barrier();
  };
  for (int g = 0; g < NG; g += 4) {
    GROUP(g, 0, 2); GROUP(g + 1, 1, 3); GROUP(g + 2, 2, 0); GROUP(g + 3, 3, 1);
  }

  #pragma unroll
  for (int mi = 0; mi < 2; mi++)
    #pragma unroll
    for (int rr = 0; rr < 16; rr++) {
      const int row = bm + wr * 64 + mi * 32 + (rr & 3) + 8 * (rr >> 2) + 4 * lkh;
      const int col = bn + wc * 32 + lr;
      C[(long)row * N + col] = enc_fp8(acc[mi][rr] * 0x1p-11f);
    }
}

// ---------------------------------------------------------------------------
// Softmax over c per (b,s) row of S (bf16); wsum[b,c] += softmax row.
// ---------------------------------------------------------------------------
__global__ __launch_bounds__(256)
void softmax_wsum(const ushort* __restrict__ S, float* __restrict__ wsum)
{
  const int b = blockIdx.x;
  const int s0 = blockIdx.y * 32;
  const int lane = threadIdx.x & 63;
  const int w = threadIdx.x >> 6;
  __shared__ float red[4][2048];
  const ushort* Sb = S + (((long)b * 1024) + s0 + w * 8) * 2048;

  float acc[32];
  #pragma unroll
  for (int i = 0; i < 32; i++) acc[i] = 0.f;
  for (int r = 0; r < 8; r++) {
    const ushort* row = Sb + (long)r * 2048;
    float v[32];
    #pragma unroll
    for (int i = 0; i < 4; i++) {
      uint4 u = *(const uint4*)(row + i * 512 + lane * 8);
      const ushort* up = (const ushort*)&u;
      #pragma unroll
      for (int j = 0; j < 8; j++) v[i * 8 + j] = bf2f(up[j]);
    }
    float m = v[0];
    #pragma unroll
    for (int i = 1; i < 32; i++) m = fmaxf(m, v[i]);
    #pragma unroll
    for (int o = 1; o < 64; o <<= 1) m = fmaxf(m, __shfl_xor(m, o));
    float ssum = 0.f;
    #pragma unroll
    for (int i = 0; i < 32; i++) { v[i] = __expf(v[i] - m); ssum += v[i]; }
    #pragma unroll
    for (int o = 1; o < 64; o <<= 1) ssum += __shfl_xor(ssum, o);
    const float inv = 1.f / ssum;
    #pragma unroll
    for (int i = 0; i < 32; i++) acc[i] += v[i] * inv;
  }
  #pragma unroll
  for (int i = 0; i < 4; i++)
    #pragma unroll
    for (int j = 0; j < 8; j++)
      red[w][i * 512 + lane * 8 + j] = acc[i * 8 + j];
  __syncthreads();
  float* wb = wsum + b * 2048;
  #pragma unroll
  for (int k = 0; k < 8; k++) {
    const int c = k * 256 + threadIdx.x;
    atomicAdd(&wb[c], red[0][c] + red[1][c] + red[2][c] + red[3][c]);
  }
}

// t[b,d] = sum_c wsum[b,c] * cyc8[b,c,d]/16
__global__ __launch_bounds__(320)
void wcyc_kernel(const unsigned char* __restrict__ cyc8, const float* __restrict__ wsum,
                 float* __restrict__ t)
{
  const int b = blockIdx.x;
  const int c0 = blockIdx.y * 64;
  const int d = threadIdx.x * 4;
  const unsigned char* cb = cyc8 + ((long)b * 2048 + c0) * 1280 + d;
  const float* wb = wsum + b * 2048 + c0;
  float4 a = {0.f, 0.f, 0.f, 0.f};
  for (int c = 0; c < 64; c++) {
    const unsigned u = *(const unsigned*)(cb + (long)c * 1280);
    const float w = wb[c];
    a.x += w * dec_fp8<0>(u); a.y += w * dec_fp8<1>(u);
    a.z += w * dec_fp8<2>(u); a.w += w * dec_fp8<3>(u);
  }
  atomicAdd(&t[b * 1280 + d + 0], a.x * 0.0625f);
  atomicAdd(&t[b * 1280 + d + 1], a.y * 0.0625f);
  atomicAdd(&t[b * 1280 + d + 2], a.z * 0.0625f);
  atomicAdd(&t[b * 1280 + d + 3], a.w * 0.0625f);
}

// xcat[b, 1280+d] += partial mean over 64-s chunk (grid 16x16).
__global__ __launch_bounds__(320)
void submean8(const unsigned char* __restrict__ sub8, float* __restrict__ xcat)
{
  const int b = blockIdx.x;
  const int s0 = blockIdx.y * 64;
  const int d = threadIdx.x * 4;
  const unsigned char* sp = sub8 + ((long)b * 1024 + s0) * 1280 + d;
  float4 a = {0.f, 0.f, 0.f, 0.f};
  for (int s = 0; s < 64; s++) {
    const unsigned u = *(const unsigned*)(sp + (long)s * 1280);
    a.x += dec_fp8<0>(u); a.y += dec_fp8<1>(u);
    a.z += dec_fp8<2>(u); a.w += dec_fp8<3>(u);
  }
  const float k = 1.f / (16.f * 1024.f);
  atomicAdd(&xcat[b * 2560 + 1280 + d + 0], a.x * k);
  atomicAdd(&xcat[b * 2560 + 1280 + d + 1], a.y * k);
  atomicAdd(&xcat[b * 2560 + 1280 + d + 2], a.z * k);
  atomicAdd(&xcat[b * 2560 + 1280 + d + 3], a.w * k);
}

// xcat[b, dp] += (1/1024) * sum_{d in 256-chunk} t[b,d] * Wv[d,dp]
// grid (5, 16, 5): d-split kills the 80-block serial-1280 latency chain.
__global__ __launch_bounds__(256)
void xv_kernel(const float* __restrict__ t, const float* __restrict__ Wv,
               float* __restrict__ xcat)
{
  const int b = blockIdx.y;
  const int dp = blockIdx.x * 256 + threadIdx.x;
  const int d0 = blockIdx.z * 256;
  __shared__ float tl[256];
  tl[threadIdx.x] = t[b * 1280 + d0 + threadIdx.x];
  __syncthreads();
  float a = 0.f;
  for (int d = 0; d < 256; d++) a += tl[d] * Wv[(long)(d0 + d) * 1280 + dp];
  atomicAdd(&xcat[b * 2560 + dp], a * (1.f / 1024.f));
}

// h1pre[b,j] += sum_{d in 320-chunk} xcat[b,d] * W1[d,j]   grid (2,16,8)
__global__ __launch_bounds__(256)
void mlp1_partial(const float* __restrict__ xcat, const float* __restrict__ W1,
                  float* __restrict__ h1pre)
{
  const int b = blockIdx.y;
  const int j = blockIdx.x * 256 + threadIdx.x;
  const int d0 = blockIdx.z * 320;
  __shared__ float xl[320];
  for (int i = threadIdx.x; i < 320; i += 256) xl[i] = xcat[b * 2560 + d0 + i];
  __syncthreads();
  float a = 0.f;
  for (int d = 0; d < 320; d++) a += xl[d] * W1[(long)(d0 + d) * 512 + j];
  atomicAdd(&h1pre[b * 512 + j], a);
}

// h = relu(h1pre + b1); h2 = relu(h @ W2 + b2); out = sigmoid(h2 @ W3 + b3)
__global__ __launch_bounds__(64)
void mlp23_kernel(const float* __restrict__ h1pre, const float* __restrict__ b1,
                  const float* __restrict__ W2, const float* __restrict__ b2,
                  const float* __restrict__ W3, const float* __restrict__ b3,
                  float* __restrict__ out)
{
  const int b = blockIdx.x;
  const int j = threadIdx.x;
  __shared__ float hl[512];
  for (int i = j; i < 512; i += 64) hl[i] = fmaxf(h1pre[b * 512 + i] + b1[i], 0.f);
  __syncthreads();
  float a = b2[j];
  for (int d = 0; d < 512; d++) a += hl[d] * W2[d * 64 + j];
  a = fmaxf(a, 0.f);
  float p = a * W3[j];
  #pragma unroll
  for (int o = 1; o < 64; o <<= 1) p += __shfl_xor(p, o);
  if (j == 0) out[b] = 1.f / (1.f + __expf(-(p + b3[0])));
}

extern "C" void kernel_launch(void* const* d_in, const int* in_sizes, int n_in,
                              void* d_out, int out_size, void* d_ws, size_t ws_size,
                              hipStream_t stream)
{
  const float* cyclase   = (const float*)d_in[0];
  const float* substrate = (const float*)d_in[1];
  const float* Wq = (const float*)d_in[4];
  const float* Wk = (const float*)d_in[5];
  const float* Wv = (const float*)d_in[6];
  const float* W1 = (const float*)d_in[7];
  const float* b1 = (const float*)d_in[8];
  const float* W2 = (const float*)d_in[9];
  const float* b2 = (const float*)d_in[10];
  const float* W3 = (const float*)d_in[11];
  const float* b3 = (const float*)d_in[12];
  float* out = (float*)d_out;
  (void)in_sizes; (void)n_in; (void)out_size; (void)ws_size;

  char* ws = (char*)d_ws;
  unsigned char* cyc8 = (unsigned char*)ws;
  char* A2 = ws + 41943040;
  ushort* Mkq   = (ushort*)(A2 + 41943040);
  ushort* Wq16  = (ushort*)(A2 + 41943040 + 3276800);
  ushort* Wk16  = (ushort*)(A2 + 41943040 + 2 * 3276800);
  unsigned char* sub8 = (unsigned char*)(A2 + 41943040 + 3 * 3276800);
  ushort* S = (ushort*)A2;                       // overlays region2
  char* B2 = A2 + 41943040 + 3 * 3276800 + 20971520;
  unsigned char* T1p8 = (unsigned char*)B2;
  unsigned char* M2_8 = (unsigned char*)(B2 + 20971520);
  char* C2 = B2 + 20971520 + 1638400;
  float* mcol  = (float*)C2;
  float* tbar  = (float*)(C2 + 8192);
  float* gsum  = (float*)(C2 + 8192 + 65536);
  float* wsum  = (float*)(C2 + 8192 + 65536 + 131072);
  float* tbuf  = (float*)(C2 + 8192 + 65536 + 2 * 131072);
  float* xcat  = (float*)(C2 + 8192 + 65536 + 2 * 131072 + 81920);
  float* h1pre = (float*)(C2 + 8192 + 65536 + 2 * 131072 + 81920 + 163840);

  hipMemsetAsync(mcol, 0, 1280 * 4, stream);
  hipMemsetAsync(wsum, 0, 16 * 2048 * 4, stream);
  hipMemsetAsync(tbuf, 0, 16 * 1280 * 4, stream);
  hipMemsetAsync(xcat, 0, 16 * 2560 * 4, stream);
  hipMemsetAsync(h1pre, 0, 16 * 512 * 4, stream);

  cvt_bf16<<<200, 256, 0, stream>>>(Wq, Wq16, 1280l * 1280 / 8);
  cvt_bf16<<<200, 256, 0, stream>>>(Wk, Wk16, 1280l * 1280 / 8);
  cyccvt<<<8192, 256, 0, stream>>>(cyclase, (unsigned*)cyc8, gsum);

  // Mkq = Wk @ Wq^T * (1/sqrt(1280))  [1280,1280] bf16
  gemm_mkq<<<100, 512, 0, stream>>>(Wk16, Wq16, Mkq, 1280, 1280, 10,
                                    0.02795084971874737f);
  colmean<<<dim3(5, 32), 256, 0, stream>>>(Mkq, mcol);
  m2cvt<<<1280, 320, 0, stream>>>(Mkq, mcol, (unsigned*)M2_8);

  // fused substrate pass: sub8 + exact tbar in one 84 MB read
  subprep<<<4096, 256, 0, stream>>>(substrate, mcol, (unsigned*)sub8, tbar);
  submean8<<<dim3(16, 16), 320, 0, stream>>>(sub8, xcat);

  // T1' = sub8 @ M2_8^T -> fp8 x4096   [16384,1280]
  gemm_f8_128<<<1280, 512, 0, stream>>>(sub8, M2_8, T1p8, 1280, 1280, 10);

  // S[b] = T1'8 @ cyc8^T * 2^-16 + tbar x gsum -> bf16  [16,1024,2048]
  gemm_f8<0, true><<<512, 512, 0, stream>>>(T1p8, cyc8, S,
      1280, 2048, 8, 4, 1024l * 1280, 2048l * 1280, 1024l * 2048, tbar, gsum);

  softmax_wsum<<<dim3(16, 32), 256, 0, stream>>>(S, wsum);
  wcyc_kernel<<<dim3(16, 32), 320, 0, stream>>>(cyc8, wsum, tbuf);
  xv_kernel<<<dim3(5, 16, 5), 256, 0, stream>>>(tbuf, Wv, xcat);
  mlp1_partial<<<dim3(2, 16, 8), 256, 0, stream>>>(xcat, W1, h1pre);
  mlp23_kernel<<<16, 64, 0, stream>>>(h1pre, b1, W2, b2, W3, b3, out);
}

// Round 17
// 380.330 us; speedup vs baseline: 1.7242x; 1.0305x over previous
//
#include <hip/hip_runtime.h>
#include <hip/hip_bf16.h>

#define DEV static __device__ __forceinline__

typedef __attribute__((ext_vector_type(16))) float f32x16;
typedef __attribute__((ext_vector_type(8)))  short bf16x8;

#if defined(__has_builtin)
#  if __has_builtin(__builtin_amdgcn_cvt_pk_fp8_f32) && __has_builtin(__builtin_amdgcn_cvt_f32_fp8)
#    define HW_FP8 1
#  endif
#endif

DEV ushort f2bf(float f){
  union { float f; unsigned u; } v; v.f = f;
  return (ushort)((v.u + 0x7FFFu + ((v.u >> 16) & 1u)) >> 16);
}
DEV float bf2f(ushort u){
  union { unsigned u; float f; } v; v.u = ((unsigned)u) << 16;
  return v.f;
}

DEV unsigned char f2e4m3_sw(float f){
  union { float f; unsigned u; } v; v.f = f;
  unsigned s = (v.u >> 24) & 0x80;
  float a = fabsf(f);
  if (a >= 448.f) return s | 0x7E;
  if (a < 0.0009765625f) return (unsigned char)s;
  if (a < 0.015625f) {
    int m = (int)rintf(a * 512.f);
    return (unsigned char)(s | (m >= 8 ? 8 : m));
  }
  unsigned ab = v.u & 0x7FFFFFFF;
  unsigned r = ab + 0x0007FFFF + ((ab >> 20) & 1);
  unsigned e = (r >> 23) - 127 + 7;
  unsigned m = (r >> 20) & 7;
  if (e > 15 || (e == 15 && m > 6)) return s | 0x7E;
  return (unsigned char)(s | (e << 3) | m);
}
DEV float e4m32f_sw(unsigned char c){
  unsigned e = (c >> 3) & 15, m = c & 7;
  float v;
  if (e) { union { unsigned u; float f; } w; w.u = ((e + 120u) << 23) | (m << 20); v = w.f; }
  else v = (float)m * 0.001953125f;
  return (c & 0x80) ? -v : v;
}

DEV unsigned pack4_fp8(float a, float b, float c, float d){
#ifdef HW_FP8
  int v = __builtin_amdgcn_cvt_pk_fp8_f32(a, b, 0, false);
  v = __builtin_amdgcn_cvt_pk_fp8_f32(c, d, v, true);
  return (unsigned)v;
#else
  return (unsigned)f2e4m3_sw(a) | ((unsigned)f2e4m3_sw(b) << 8)
       | ((unsigned)f2e4m3_sw(c) << 16) | ((unsigned)f2e4m3_sw(d) << 24);
#endif
}
DEV unsigned char enc_fp8(float a){
#ifdef HW_FP8
  return (unsigned char)(__builtin_amdgcn_cvt_pk_fp8_f32(a, a, 0, false) & 0xFF);
#else
  return f2e4m3_sw(a);
#endif
}
template<int SEL>
DEV float dec_fp8(unsigned u){
#ifdef HW_FP8
  return __builtin_amdgcn_cvt_f32_fp8((int)u, SEL);
#else
  return e4m32f_sw((u >> (SEL * 8)) & 0xFF);
#endif
}

// async global->LDS, 16B per lane; LDS dest is wave-uniform base + lane*16.
DEV void gload16(const void* g, void* l) {
  __builtin_amdgcn_global_load_lds(
      (const __attribute__((address_space(1))) unsigned*)g,
      (__attribute__((address_space(3))) unsigned*)l, 16, 0, 0);
}

// ---------------------------------------------------------------------------
// Elementwise f32 -> bf16 (Wq/Wk only).
// ---------------------------------------------------------------------------
__global__ __launch_bounds__(256)
void cvt_bf16(const float* __restrict__ src, ushort* __restrict__ dst, long n8)
{
  const long stride = (long)gridDim.x * 256;
  for (long i = (long)blockIdx.x * 256 + threadIdx.x; i < n8; i += stride) {
    const float4 a = *(const float4*)(src + i * 8);
    const float4 b = *(const float4*)(src + i * 8 + 4);
    union { ushort u[8]; uint4 v; } pk;
    pk.u[0] = f2bf(a.x); pk.u[1] = f2bf(a.y); pk.u[2] = f2bf(a.z); pk.u[3] = f2bf(a.w);
    pk.u[4] = f2bf(b.x); pk.u[5] = f2bf(b.y); pk.u[6] = f2bf(b.z); pk.u[7] = f2bf(b.w);
    *(uint4*)(dst + i * 8) = pk.v;
  }
}

// cyclase: f32 row -> fp8 row (x16) + exact f32 rowsum. Wave per row.
__global__ __launch_bounds__(256)
void cyccvt(const float* __restrict__ cyc, unsigned* __restrict__ cyc8w,
            float* __restrict__ gsum)
{
  const int lane = threadIdx.x & 63, wid = threadIdx.x >> 6;
  const long row = (long)blockIdx.x * 4 + wid;   // 32768 rows
  const float* src = cyc + row * 1280;
  unsigned* dst = cyc8w + row * 320;
  float s = 0.f;
  #pragma unroll
  for (int i = 0; i < 5; i++) {
    const int d = i * 256 + lane * 4;
    const float4 v = *(const float4*)(src + d);
    s += v.x + v.y + v.z + v.w;
    dst[d >> 2] = pack4_fp8(v.x * 16.f, v.y * 16.f, v.z * 16.f, v.w * 16.f);
  }
  #pragma unroll
  for (int o = 1; o < 64; o <<= 1) s += __shfl_xor(s, o);
  if (lane == 0) gsum[row] = s;
}

// substrate fused pass: f32 row read ONCE -> sub8 (fp8 x16) + exact tbar.
__global__ __launch_bounds__(256)
void subprep(const float* __restrict__ sub, const float* __restrict__ mcol,
             unsigned* __restrict__ sub8w, float* __restrict__ tbar)
{
  __shared__ float mc[1280];
  for (int i = threadIdx.x; i < 1280; i += 256) mc[i] = mcol[i];
  __syncthreads();
  const int lane = threadIdx.x & 63, wid = threadIdx.x >> 6;
  const long row = (long)blockIdx.x * 4 + wid;   // 16384 rows
  const float4* sp = (const float4*)(sub + row * 1280);
  unsigned* dp = sub8w + row * 320;
  float d = 0.f;
  #pragma unroll
  for (int i = 0; i < 5; i++) {
    const int c = i * 64 + lane;
    const float4 v = sp[c];
    d += v.x * mc[c * 4] + v.y * mc[c * 4 + 1] + v.z * mc[c * 4 + 2] + v.w * mc[c * 4 + 3];
    dp[c] = pack4_fp8(v.x * 16.f, v.y * 16.f, v.z * 16.f, v.w * 16.f);
  }
  #pragma unroll
  for (int o = 1; o < 64; o <<= 1) d += __shfl_xor(d, o);
  if (lane == 0) tbar[row] = d;
}

// ---------------------------------------------------------------------------
// bf16 GEMM 8-phase (r6 structure, BM=128) — Mkq only (small).
// ---------------------------------------------------------------------------
__global__ __launch_bounds__(512, 4)
void gemm_mkq(const ushort* __restrict__ A, const ushort* __restrict__ B,
              ushort* __restrict__ C, int K, int N, int nbx, float scale)
{
  __shared__ __align__(16) ushort As[4][4][128][8];
  __shared__ __align__(16) ushort Bs[4][4][128][8];
  const int tid = threadIdx.x, lane = tid & 63, wid = tid >> 6;
  const int wr = wid >> 2, wc = wid & 3;
  const int bx = blockIdx.x % nbx, by = blockIdx.x / nbx;
  const int bm = by * 128, bn = bx * 128;

  f32x16 acc[2];
  #pragma unroll
  for (int i = 0; i < 2; i++)
    #pragma unroll
    for (int e = 0; e < 16; e++) acc[i][e] = 0.f;

  const int kbA = wid >> 1, rqA = wid & 1;
  const ushort* agp = A + (long)(bm + rqA * 64 + lane) * K + kbA * 8;
  const ushort* bgp = B + (long)(bn + rqA * 64 + lane) * K + kbA * 8;
  auto STAGE = [&](int g, int rg) {
    gload16(agp + g * 32, &As[rg][kbA][rqA * 64][0]);
    gload16(bgp + g * 32, &Bs[rg][kbA][rqA * 64][0]);
  };
  const int NG = K >> 5;
  STAGE(0, 0); STAGE(1, 1);
  asm volatile("s_waitcnt vmcnt(2)" ::: "memory");
  __builtin_amdgcn_s_barrier();
  const int lkh = lane >> 5, lr = lane & 31;
  auto GROUP = [&](int g, int rg, int rg2) {
    bf16x8 av[2][2], bv[2];
    #pragma unroll
    for (int kf = 0; kf < 2; kf++) {
      #pragma unroll
      for (int mi = 0; mi < 2; mi++)
        av[mi][kf] = *(const bf16x8*)&As[rg][kf * 2 + lkh][wr * 64 + mi * 32 + lr][0];
      bv[kf] = *(const bf16x8*)&Bs[rg][kf * 2 + lkh][wc * 32 + lr][0];
    }
    if (g + 2 < NG) STAGE(g + 2, rg2);
    __builtin_amdgcn_s_barrier();
    __builtin_amdgcn_s_setprio(1);
    #pragma unroll
    for (int mi = 0; mi < 2; mi++)
      #pragma unroll
      for (int kf = 0; kf < 2; kf++)
        acc[mi] = __builtin_amdgcn_mfma_f32_32x32x16_bf16(av[mi][kf], bv[kf], acc[mi], 0, 0, 0);
    __builtin_amdgcn_s_setprio(0);
    if (g + 2 < NG)      asm volatile("s_waitcnt vmcnt(2)" ::: "memory");
    else if (g + 1 < NG) asm volatile("s_waitcnt vmcnt(0)" ::: "memory");
    __builtin_amdgcn_s_barrier();
  };
  for (int g = 0; g < NG; g += 4) {
    GROUP(g, 0, 2); GROUP(g + 1, 1, 3); GROUP(g + 2, 2, 0); GROUP(g + 3, 3, 1);
  }
  #pragma unroll
  for (int mi = 0; mi < 2; mi++)
    #pragma unroll
    for (int rr = 0; rr < 16; rr++) {
      const int row = bm + wr * 64 + mi * 32 + (rr & 3) + 8 * (rr >> 2) + 4 * lkh;
      const int col = bn + wc * 32 + lr;
      C[(long)row * N + col] = f2bf(acc[mi][rr] * scale);
    }
}

// mcol[d] += partial col-mean.  Grid (5, 32).
__global__ __launch_bounds__(256)
void colmean(const ushort* __restrict__ Mkq, float* __restrict__ mcol)
{
  const int d = blockIdx.x * 256 + threadIdx.x;
  const int r0 = blockIdx.y * 40;
  float s = 0.f;
  for (int j = 0; j < 40; j++) s += bf2f(Mkq[(long)(r0 + j) * 1280 + d]);
  atomicAdd(&mcol[d], s * (1.f / 1280.f));
}

// M2_8[j][d] = e4m3((Mkq[j][d] - mcol[d]) * 2^19)
__global__ __launch_bounds__(320)
void m2cvt(const ushort* __restrict__ Mkq, const float* __restrict__ mcol,
           unsigned* __restrict__ M2w)
{
  const int j = blockIdx.x;
  const int d = threadIdx.x * 4;
  const ushort* mr = Mkq + (long)j * 1280 + d;
  const float* mc = mcol + d;
  M2w[j * 320 + threadIdx.x] = pack4_fp8(
      (bf2f(mr[0]) - mc[0]) * 524288.f, (bf2f(mr[1]) - mc[1]) * 524288.f,
      (bf2f(mr[2]) - mc[2]) * 524288.f, (bf2f(mr[3]) - mc[3]) * 524288.f);
}

// ---------------------------------------------------------------------------
// fp8 GEMM 256x256 (r10/r14 config — best measured): ring-4, depth-2,
// gload16, MFMA 32x32x16_fp8_fp8.
// MODE 0: C = bf16( acc*2^-16 + tbar[z*1024+row]*gsum[z*2048+col] )   (S)
// ---------------------------------------------------------------------------
template<int MODE, bool BY_FAST>
__global__ __launch_bounds__(512, 2)
void gemm_f8(const unsigned char* __restrict__ A, const unsigned char* __restrict__ B,
             void* __restrict__ Cv, int K, int N, int nbx, int nby,
             long sA, long sB, long sC,
             const float* __restrict__ tbar, const float* __restrict__ gsum)
{
  __shared__ __align__(16) unsigned char As[4][4][256][16];  // 64 KB
  __shared__ __align__(16) unsigned char Bs[4][4][256][16];  // 64 KB
  const int tid = threadIdx.x, lane = tid & 63, wid = tid >> 6;
  const int wr = wid >> 2, wc = wid & 3;

  const int nwg = gridDim.x;
  const int q = nwg >> 3, r = nwg & 7;
  const int xcd = blockIdx.x & 7, lid = blockIdx.x >> 3;
  const int id = (xcd < r ? xcd * (q + 1) : r * (q + 1) + (xcd - r) * q) + lid;
  const int per = nbx * nby;
  const int z = id / per, rem = id - z * per;
  const int bx = BY_FAST ? rem / nby : rem % nbx;
  const int by = BY_FAST ? rem % nby : rem / nbx;
  const int bm = by * 256, bn = bx * 256;
  const long Ab = (long)z * sA, Bb = (long)z * sB, Cb = (long)z * sC;

  f32x16 acc[4][2];
  #pragma unroll
  for (int i = 0; i < 4; i++)
    #pragma unroll
    for (int j = 0; j < 2; j++)
      #pragma unroll
      for (int e = 0; e < 16; e++) acc[i][j][e] = 0.f;

  const int c0 = wid * 2, c1 = wid * 2 + 1;
  const int kb0 = c0 >> 2, rq0 = c0 & 3, kb1 = c1 >> 2, rq1 = c1 & 3;
  const unsigned char* ag0 = A + Ab + (long)(bm + rq0 * 64 + lane) * K + kb0 * 16;
  const unsigned char* ag1 = A + Ab + (long)(bm + rq1 * 64 + lane) * K + kb1 * 16;
  const unsigned char* bg0 = B + Bb + (long)(bn + rq0 * 64 + lane) * K + kb0 * 16;
  const unsigned char* bg1 = B + Bb + (long)(bn + rq1 * 64 + lane) * K + kb1 * 16;
  auto STAGE_A = [&](int g, int rg) {
    gload16(ag0 + g * 64, &As[rg][kb0][rq0 * 64][0]);
    gload16(ag1 + g * 64, &As[rg][kb1][rq1 * 64][0]);
  };
  auto STAGE_B = [&](int g, int rg) {
    gload16(bg0 + g * 64, &Bs[rg][kb0][rq0 * 64][0]);
    gload16(bg1 + g * 64, &Bs[rg][kb1][rq1 * 64][0]);
  };

  const int NG = K >> 6;  // 64-K groups, multiple of 4
  STAGE_A(0, 0); STAGE_B(0, 0); STAGE_A(1, 1); STAGE_B(1, 1);
  asm volatile("s_waitcnt vmcnt(4)" ::: "memory");
  __builtin_amdgcn_s_barrier();

  const int lkh = lane >> 5, lr = lane & 31;

  auto GROUP = [&](int g, int rg, int rg2) {
    const bool pre = (g + 2 < NG);
    long av[2][4], bv[2][4];
    #pragma unroll
    for (int kf = 0; kf < 4; kf++) {
      #pragma unroll
      for (int mi = 0; mi < 2; mi++)
        av[mi][kf] = *(const long*)&As[rg][kf][wr * 128 + mi * 32 + lr][lkh * 8];
      #pragma unroll
      for (int ni = 0; ni < 2; ni++)
        bv[ni][kf] = *(const long*)&Bs[rg][kf][wc * 64 + ni * 32 + lr][lkh * 8];
    }
    if (pre) STAGE_A(g + 2, rg2);
    __builtin_amdgcn_s_barrier();
    __builtin_amdgcn_s_setprio(1);
    #pragma unroll
    for (int kf = 0; kf < 4; kf++)
      #pragma unroll
      for (int mi = 0; mi < 2; mi++)
        #pragma unroll
        for (int ni = 0; ni < 2; ni++)
          acc[mi][ni] = __builtin_amdgcn_mfma_f32_32x32x16_fp8_fp8(av[mi][kf], bv[ni][kf], acc[mi][ni], 0, 0, 0);
    __builtin_amdgcn_s_setprio(0);
    __builtin_amdgcn_s_barrier();
    #pragma unroll
    for (int kf = 0; kf < 4; kf++)
      #pragma unroll
      for (int mi = 0; mi < 2; mi++)
        av[mi][kf] = *(const long*)&As[rg][kf][wr * 128 + (mi + 2) * 32 + lr][lkh * 8];
    if (pre) STAGE_B(g + 2, rg2);
    __builtin_amdgcn_s_barrier();
    __builtin_amdgcn_s_setprio(1);
    #pragma unroll
    for (int kf = 0; kf < 4; kf++)
      #pragma unroll
      for (int mi = 0; mi < 2; mi++)
        #pragma unroll
        for (int ni = 0; ni < 2; ni++)
          acc[mi + 2][ni] = __builtin_amdgcn_mfma_f32_32x32x16_fp8_fp8(av[mi][kf], bv[ni][kf], acc[mi + 2][ni], 0, 0, 0);
    __builtin_amdgcn_s_setprio(0);
    if (pre)             asm volatile("s_waitcnt vmcnt(4)" ::: "memory");
    else if (g + 1 < NG) asm volatile("s_waitcnt vmcnt(0)" ::: "memory");
    __builtin_amdgcn_s_barrier();
  };

  for (int g = 0; g < NG; g += 4) {
    GROUP(g, 0, 2); GROUP(g + 1, 1, 3); GROUP(g + 2, 2, 0); GROUP(g + 3, 3, 1);
  }

  // C/D 32x32: col=lane&31, row=(reg&3)+8*(reg>>2)+4*(lane>>5)
  #pragma unroll
  for (int mi = 0; mi < 4; mi++)
    #pragma unroll
    for (int ni = 0; ni < 2; ni++)
      #pragma unroll
      for (int rr = 0; rr < 16; rr++) {
        const int row = bm + wr * 128 + mi * 32 + (rr & 3) + 8 * (rr >> 2) + 4 * lkh;
        const int col = bn + wc * 64 + ni * 32 + lr;
        if constexpr (MODE == 0) {
          const float v = acc[mi][ni][rr] * 0x1p-16f
                        + tbar[(long)z * 1024 + row] * gsum[(long)z * 2048 + col];
          ((ushort*)Cv)[Cb + (long)row * N + col] = f2bf(v);
        } else {
          ((unsigned char*)Cv)[Cb + (long)row * N + col] = enc_fp8(acc[mi][ni][rr] * 0x1p-11f);
        }
      }
}

// ---------------------------------------------------------------------------
// fp8 GEMM 128x128 (T1', r14 config): 2 blocks/CU, 1280 blocks = 5 rounds.
// C = e4m3( acc * 2^-11 ).
// ---------------------------------------------------------------------------
__global__ __launch_bounds__(512, 4)
void gemm_f8_128(const unsigned char* __restrict__ A, const unsigned char* __restrict__ B,
                 unsigned char* __restrict__ C, int K, int N, int nbx)
{
  __shared__ __align__(16) unsigned char As[4][4][128][16];  // 32 KB
  __shared__ __align__(16) unsigned char Bs[4][4][128][16];  // 32 KB
  const int tid = threadIdx.x, lane = tid & 63, wid = tid >> 6;
  const int wr = wid >> 2, wc = wid & 3;

  const int nwg = gridDim.x;
  const int q = nwg >> 3, r = nwg & 7;
  const int xcd = blockIdx.x & 7, lid = blockIdx.x >> 3;
  const int id = (xcd < r ? xcd * (q + 1) : r * (q + 1) + (xcd - r) * q) + lid;
  const int bx = id % nbx, by = id / nbx;
  const int bm = by * 128, bn = bx * 128;

  f32x16 acc[2];
  #pragma unroll
  for (int i = 0; i < 2; i++)
    #pragma unroll
    for (int e = 0; e < 16; e++) acc[i][e] = 0.f;

  const int kbA = wid >> 1, rhA = wid & 1;
  const unsigned char* agp = A + (long)(bm + rhA * 64 + lane) * K + kbA * 16;
  const unsigned char* bgp = B + (long)(bn + rhA * 64 + lane) * K + kbA * 16;
  auto STAGE = [&](int g, int rg) {
    gload16(agp + g * 64, &As[rg][kbA][rhA * 64][0]);
    gload16(bgp + g * 64, &Bs[rg][kbA][rhA * 64][0]);
  };
  const int NG = K >> 6;  // K=1280 -> 20
  STAGE(0, 0); STAGE(1, 1);
  asm volatile("s_waitcnt vmcnt(2)" ::: "memory");
  __builtin_amdgcn_s_barrier();

  const int lkh = lane >> 5, lr = lane & 31;

  auto GROUP = [&](int g, int rg, int rg2) {
    long av[2][4], bv[4];
    #pragma unroll
    for (int kf = 0; kf < 4; kf++) {
      #pragma unroll
      for (int mi = 0; mi < 2; mi++)
        av[mi][kf] = *(const long*)&As[rg][kf][wr * 64 + mi * 32 + lr][lkh * 8];
      bv[kf] = *(const long*)&Bs[rg][kf][wc * 32 + lr][lkh * 8];
    }
    if (g + 2 < NG) STAGE(g + 2, rg2);
    __builtin_amdgcn_s_barrier();
    __builtin_amdgcn_s_setprio(1);
    #pragma unroll
    for (int kf = 0; kf < 4; kf++)
      #pragma unroll
      for (int mi = 0; mi < 2; mi++)
        acc[mi] = __builtin_amdgcn_mfma_f32_32x32x16_fp8_fp8(av[mi][kf], bv[kf], acc[mi], 0, 0, 0);
    __builtin_amdgcn_s_setprio(0);
    if (g + 2 < NG)      asm volatile("s_waitcnt vmcnt(2)" ::: "memory");
    else if (g + 1 < NG) asm volatile("s_waitcnt vmcnt(0)" ::: "memory");
    __builtin_amdgcn_s_barrier();
  };
  for (int g = 0; g < NG; g += 4) {
    GROUP(g, 0, 2); GROUP(g + 1, 1, 3); GROUP(g + 2, 2, 0); GROUP(g + 3, 3, 1);
  }

  #pragma unroll
  for (int mi = 0; mi < 2; mi++)
    #pragma unroll
    for (int rr = 0; rr < 16; rr++) {
      const int row = bm + wr * 64 + mi * 32 + (rr & 3) + 8 * (rr >> 2) + 4 * lkh;
      const int col = bn + wc * 32 + lr;
      C[(long)row * N + col] = enc_fp8(acc[mi][rr] * 0x1p-11f);
    }
}

// ---------------------------------------------------------------------------
// Softmax over c per (b,s) row of S (bf16); wsum[b,c] += softmax row.
// ---------------------------------------------------------------------------
__global__ __launch_bounds__(256)
void softmax_wsum(const ushort* __restrict__ S, float* __restrict__ wsum)
{
  const int b = blockIdx.x;
  const int s0 = blockIdx.y * 32;
  const int lane = threadIdx.x & 63;
  const int w = threadIdx.x >> 6;
  __shared__ float red[4][2048];
  const ushort* Sb = S + (((long)b * 1024) + s0 + w * 8) * 2048;

  float acc[32];
  #pragma unroll
  for (int i = 0; i < 32; i++) acc[i] = 0.f;
  for (int r = 0; r < 8; r++) {
    const ushort* row = Sb + (long)r * 2048;
    float v[32];
    #pragma unroll
    for (int i = 0; i < 4; i++) {
      uint4 u = *(const uint4*)(row + i * 512 + lane * 8);
      const ushort* up = (const ushort*)&u;
      #pragma unroll
      for (int j = 0; j < 8; j++) v[i * 8 + j] = bf2f(up[j]);
    }
    float m = v[0];
    #pragma unroll
    for (int i = 1; i < 32; i++) m = fmaxf(m, v[i]);
    #pragma unroll
    for (int o = 1; o < 64; o <<= 1) m = fmaxf(m, __shfl_xor(m, o));
    float ssum = 0.f;
    #pragma unroll
    for (int i = 0; i < 32; i++) { v[i] = __expf(v[i] - m); ssum += v[i]; }
    #pragma unroll
    for (int o = 1; o < 64; o <<= 1) ssum += __shfl_xor(ssum, o);
    const float inv = 1.f / ssum;
    #pragma unroll
    for (int i = 0; i < 32; i++) acc[i] += v[i] * inv;
  }
  #pragma unroll
  for (int i = 0; i < 4; i++)
    #pragma unroll
    for (int j = 0; j < 8; j++)
      red[w][i * 512 + lane * 8 + j] = acc[i * 8 + j];
  __syncthreads();
  float* wb = wsum + b * 2048;
  #pragma unroll
  for (int k = 0; k < 8; k++) {
    const int c = k * 256 + threadIdx.x;
    atomicAdd(&wb[c], red[0][c] + red[1][c] + red[2][c] + red[3][c]);
  }
}

// t[b,d] = sum_c wsum[b,c] * cyc8[b,c,d]/16
__global__ __launch_bounds__(320)
void wcyc_kernel(const unsigned char* __restrict__ cyc8, const float* __restrict__ wsum,
                 float* __restrict__ t)
{
  const int b = blockIdx.x;
  const int c0 = blockIdx.y * 64;
  const int d = threadIdx.x * 4;
  const unsigned char* cb = cyc8 + ((long)b * 2048 + c0) * 1280 + d;
  const float* wb = wsum + b * 2048 + c0;
  float4 a = {0.f, 0.f, 0.f, 0.f};
  for (int c = 0; c < 64; c++) {
    const unsigned u = *(const unsigned*)(cb + (long)c * 1280);
    const float w = wb[c];
    a.x += w * dec_fp8<0>(u); a.y += w * dec_fp8<1>(u);
    a.z += w * dec_fp8<2>(u); a.w += w * dec_fp8<3>(u);
  }
  atomicAdd(&t[b * 1280 + d + 0], a.x * 0.0625f);
  atomicAdd(&t[b * 1280 + d + 1], a.y * 0.0625f);
  atomicAdd(&t[b * 1280 + d + 2], a.z * 0.0625f);
  atomicAdd(&t[b * 1280 + d + 3], a.w * 0.0625f);
}

// xcat[b, 1280+d] += partial mean over 64-s chunk (grid 16x16).
__global__ __launch_bounds__(320)
void submean8(const unsigned char* __restrict__ sub8, float* __restrict__ xcat)
{
  const int b = blockIdx.x;
  const int s0 = blockIdx.y * 64;
  const int d = threadIdx.x * 4;
  const unsigned char* sp = sub8 + ((long)b * 1024 + s0) * 1280 + d;
  float4 a = {0.f, 0.f, 0.f, 0.f};
  for (int s = 0; s < 64; s++) {
    const unsigned u = *(const unsigned*)(sp + (long)s * 1280);
    a.x += dec_fp8<0>(u); a.y += dec_fp8<1>(u);
    a.z += dec_fp8<2>(u); a.w += dec_fp8<3>(u);
  }
  const float k = 1.f / (16.f * 1024.f);
  atomicAdd(&xcat[b * 2560 + 1280 + d + 0], a.x * k);
  atomicAdd(&xcat[b * 2560 + 1280 + d + 1], a.y * k);
  atomicAdd(&xcat[b * 2560 + 1280 + d + 2], a.z * k);
  atomicAdd(&xcat[b * 2560 + 1280 + d + 3], a.w * k);
}

// ---------------------------------------------------------------------------
// xv_fused: xcat[b, dp] += (1/1024) * sum_d t[b,d] * Wv[d,dp], batch-fused:
// block = (dp-64-block, d-256-chunk); Wv tile read ONCE for all 16 batches
// (was 16x redundant = 105 MB; now 6.5 MB). 4 thread-groups split the
// d-range; LDS reduce; one atomicAdd per output.
// Grid (20, 5), 256 threads.
// ---------------------------------------------------------------------------
__global__ __launch_bounds__(256)
void xv_fused(const float* __restrict__ t, const float* __restrict__ Wv,
              float* __restrict__ xcat)
{
  const int dp0 = blockIdx.x * 64;
  const int d0 = blockIdx.y * 256;
  __shared__ float tl[16 * 256];       // t[b][d-chunk]
  __shared__ float red[4][64][16];
  for (int i = threadIdx.x; i < 16 * 256; i += 256) {
    const int b = i >> 8, d = i & 255;
    tl[i] = t[b * 1280 + d0 + d];
  }
  __syncthreads();
  const int dpi = threadIdx.x & 63;
  const int grp = threadIdx.x >> 6;
  float acc[16];
  #pragma unroll
  for (int b = 0; b < 16; b++) acc[b] = 0.f;
  for (int dd = 0; dd < 64; dd++) {
    const int d = grp * 64 + dd;
    const float w = Wv[(long)(d0 + d) * 1280 + dp0 + dpi];
    #pragma unroll
    for (int b = 0; b < 16; b++) acc[b] += w * tl[b * 256 + d];
  }
  #pragma unroll
  for (int b = 0; b < 16; b++) red[grp][dpi][b] = acc[b];
  __syncthreads();
  // 1024 outputs / 256 threads = 4 each
  #pragma unroll
  for (int k = 0; k < 4; k++) {
    const int o = k * 256 + threadIdx.x;   // o = dp*16 + b
    const int dp = o >> 4, b = o & 15;
    const float v = red[0][dp][b] + red[1][dp][b] + red[2][dp][b] + red[3][dp][b];
    atomicAdd(&xcat[b * 2560 + dp0 + dp], v * (1.f / 1024.f));
  }
}

// ---------------------------------------------------------------------------
// mlp1_fused: h1pre[b,j] += sum_d xcat[b,d] * W1[d,j], batch-fused:
// block = (j-64-block, d-320-chunk); W1 tile read ONCE for all 16 batches
// (was 16x redundant = 84 MB; now 5.2 MB). Grid (8, 8), 256 threads.
// ---------------------------------------------------------------------------
__global__ __launch_bounds__(256)
void mlp1_fused(const float* __restrict__ xcat, const float* __restrict__ W1,
                float* __restrict__ h1pre)
{
  const int j0 = blockIdx.x * 64;
  const int d0 = blockIdx.y * 320;
  __shared__ float xl[16 * 320];       // xcat[b][d-chunk]  (20 KB)
  __shared__ float red[4][64][16];     // 16 KB
  for (int i = threadIdx.x; i < 16 * 320; i += 256) {
    const int b = i / 320, d = i % 320;
    xl[i] = xcat[b * 2560 + d0 + d];
  }
  __syncthreads();
  const int ji = threadIdx.x & 63;
  const int grp = threadIdx.x >> 6;
  float acc[16];
  #pragma unroll
  for (int b = 0; b < 16; b++) acc[b] = 0.f;
  for (int dd = 0; dd < 80; dd++) {
    const int d = grp * 80 + dd;
    const float w = W1[(long)(d0 + d) * 512 + j0 + ji];
    #pragma unroll
    for (int b = 0; b < 16; b++) acc[b] += w * xl[b * 320 + d];
  }
  #pragma unroll
  for (int b = 0; b < 16; b++) red[grp][ji][b] = acc[b];
  __syncthreads();
  #pragma unroll
  for (int k = 0; k < 4; k++) {
    const int o = k * 256 + threadIdx.x;   // o = j*16 + b
    const int j = o >> 4, b = o & 15;
    const float v = red[0][j][b] + red[1][j][b] + red[2][j][b] + red[3][j][b];
    atomicAdd(&h1pre[b * 512 + j0 + j], v);
  }
}

// h = relu(h1pre + b1); h2 = relu(h @ W2 + b2); out = sigmoid(h2 @ W3 + b3)
__global__ __launch_bounds__(64)
void mlp23_kernel(const float* __restrict__ h1pre, const float* __restrict__ b1,
                  const float* __restrict__ W2, const float* __restrict__ b2,
                  const float* __restrict__ W3, const float* __restrict__ b3,
                  float* __restrict__ out)
{
  const int b = blockIdx.x;
  const int j = threadIdx.x;
  __shared__ float hl[512];
  for (int i = j; i < 512; i += 64) hl[i] = fmaxf(h1pre[b * 512 + i] + b1[i], 0.f);
  __syncthreads();
  float a = b2[j];
  for (int d = 0; d < 512; d++) a += hl[d] * W2[d * 64 + j];
  a = fmaxf(a, 0.f);
  float p = a * W3[j];
  #pragma unroll
  for (int o = 1; o < 64; o <<= 1) p += __shfl_xor(p, o);
  if (j == 0) out[b] = 1.f / (1.f + __expf(-(p + b3[0])));
}

extern "C" void kernel_launch(void* const* d_in, const int* in_sizes, int n_in,
                              void* d_out, int out_size, void* d_ws, size_t ws_size,
                              hipStream_t stream)
{
  const float* cyclase   = (const float*)d_in[0];
  const float* substrate = (const float*)d_in[1];
  const float* Wq = (const float*)d_in[4];
  const float* Wk = (const float*)d_in[5];
  const float* Wv = (const float*)d_in[6];
  const float* W1 = (const float*)d_in[7];
  const float* b1 = (const float*)d_in[8];
  const float* W2 = (const float*)d_in[9];
  const float* b2 = (const float*)d_in[10];
  const float* W3 = (const float*)d_in[11];
  const float* b3 = (const float*)d_in[12];
  float* out = (float*)d_out;
  (void)in_sizes; (void)n_in; (void)out_size; (void)ws_size;

  char* ws = (char*)d_ws;
  unsigned char* cyc8 = (unsigned char*)ws;
  char* A2 = ws + 41943040;
  ushort* Mkq   = (ushort*)(A2 + 41943040);
  ushort* Wq16  = (ushort*)(A2 + 41943040 + 3276800);
  ushort* Wk16  = (ushort*)(A2 + 41943040 + 2 * 3276800);
  unsigned char* sub8 = (unsigned char*)(A2 + 41943040 + 3 * 3276800);
  ushort* S = (ushort*)A2;                       // overlays region2
  char* B2 = A2 + 41943040 + 3 * 3276800 + 20971520;
  unsigned char* T1p8 = (unsigned char*)B2;
  unsigned char* M2_8 = (unsigned char*)(B2 + 20971520);
  char* C2 = B2 + 20971520 + 1638400;
  float* mcol  = (float*)C2;
  float* tbar  = (float*)(C2 + 8192);
  float* gsum  = (float*)(C2 + 8192 + 65536);
  float* wsum  = (float*)(C2 + 8192 + 65536 + 131072);
  float* tbuf  = (float*)(C2 + 8192 + 65536 + 2 * 131072);
  float* xcat  = (float*)(C2 + 8192 + 65536 + 2 * 131072 + 81920);
  float* h1pre = (float*)(C2 + 8192 + 65536 + 2 * 131072 + 81920 + 163840);

  hipMemsetAsync(mcol, 0, 1280 * 4, stream);
  hipMemsetAsync(wsum, 0, 16 * 2048 * 4, stream);
  hipMemsetAsync(tbuf, 0, 16 * 1280 * 4, stream);
  hipMemsetAsync(xcat, 0, 16 * 2560 * 4, stream);
  hipMemsetAsync(h1pre, 0, 16 * 512 * 4, stream);

  cvt_bf16<<<200, 256, 0, stream>>>(Wq, Wq16, 1280l * 1280 / 8);
  cvt_bf16<<<200, 256, 0, stream>>>(Wk, Wk16, 1280l * 1280 / 8);
  cyccvt<<<8192, 256, 0, stream>>>(cyclase, (unsigned*)cyc8, gsum);

  // Mkq = Wk @ Wq^T * (1/sqrt(1280))  [1280,1280] bf16
  gemm_mkq<<<100, 512, 0, stream>>>(Wk16, Wq16, Mkq, 1280, 1280, 10,
                                    0.02795084971874737f);
  colmean<<<dim3(5, 32), 256, 0, stream>>>(Mkq, mcol);
  m2cvt<<<1280, 320, 0, stream>>>(Mkq, mcol, (unsigned*)M2_8);

  // fused substrate pass: sub8 + exact tbar in one 84 MB read
  subprep<<<4096, 256, 0, stream>>>(substrate, mcol, (unsigned*)sub8, tbar);
  submean8<<<dim3(16, 16), 320, 0, stream>>>(sub8, xcat);

  // T1' = sub8 @ M2_8^T -> fp8 x4096   [16384,1280]
  gemm_f8_128<<<1280, 512, 0, stream>>>(sub8, M2_8, T1p8, 1280, 1280, 10);

  // S[b] = T1'8 @ cyc8^T * 2^-16 + tbar x gsum -> bf16  [16,1024,2048]
  gemm_f8<0, true><<<512, 512, 0, stream>>>(T1p8, cyc8, S,
      1280, 2048, 8, 4, 1024l * 1280, 2048l * 1280, 1024l * 2048, tbar, gsum);

  softmax_wsum<<<dim3(16, 32), 256, 0, stream>>>(S, wsum);
  wcyc_kernel<<<dim3(16, 32), 320, 0, stream>>>(cyc8, wsum, tbuf);
  xv_fused<<<dim3(20, 5), 256, 0, stream>>>(tbuf, Wv, xcat);
  mlp1_fused<<<dim3(8, 8), 256, 0, stream>>>(xcat, W1, h1pre);
  mlp23_kernel<<<16, 64, 0, stream>>>(h1pre, b1, W2, b2, W3, b3, out);
}

// Round 18
// 368.078 us; speedup vs baseline: 1.7816x; 1.0333x over previous
//
#include <hip/hip_runtime.h>
#include <hip/hip_bf16.h>

#define DEV static __device__ __forceinline__

typedef __attribute__((ext_vector_type(16))) float f32x16;
typedef __attribute__((ext_vector_type(8)))  short bf16x8;

#if defined(__has_builtin)
#  if __has_builtin(__builtin_amdgcn_cvt_pk_fp8_f32) && __has_builtin(__builtin_amdgcn_cvt_f32_fp8)
#    define HW_FP8 1
#  endif
#endif

DEV ushort f2bf(float f){
  union { float f; unsigned u; } v; v.f = f;
  return (ushort)((v.u + 0x7FFFu + ((v.u >> 16) & 1u)) >> 16);
}
DEV float bf2f(ushort u){
  union { unsigned u; float f; } v; v.u = ((unsigned)u) << 16;
  return v.f;
}

DEV unsigned char f2e4m3_sw(float f){
  union { float f; unsigned u; } v; v.f = f;
  unsigned s = (v.u >> 24) & 0x80;
  float a = fabsf(f);
  if (a >= 448.f) return s | 0x7E;
  if (a < 0.0009765625f) return (unsigned char)s;
  if (a < 0.015625f) {
    int m = (int)rintf(a * 512.f);
    return (unsigned char)(s | (m >= 8 ? 8 : m));
  }
  unsigned ab = v.u & 0x7FFFFFFF;
  unsigned r = ab + 0x0007FFFF + ((ab >> 20) & 1);
  unsigned e = (r >> 23) - 127 + 7;
  unsigned m = (r >> 20) & 7;
  if (e > 15 || (e == 15 && m > 6)) return s | 0x7E;
  return (unsigned char)(s | (e << 3) | m);
}
DEV float e4m32f_sw(unsigned char c){
  unsigned e = (c >> 3) & 15, m = c & 7;
  float v;
  if (e) { union { unsigned u; float f; } w; w.u = ((e + 120u) << 23) | (m << 20); v = w.f; }
  else v = (float)m * 0.001953125f;
  return (c & 0x80) ? -v : v;
}

DEV unsigned pack4_fp8(float a, float b, float c, float d){
#ifdef HW_FP8
  int v = __builtin_amdgcn_cvt_pk_fp8_f32(a, b, 0, false);
  v = __builtin_amdgcn_cvt_pk_fp8_f32(c, d, v, true);
  return (unsigned)v;
#else
  return (unsigned)f2e4m3_sw(a) | ((unsigned)f2e4m3_sw(b) << 8)
       | ((unsigned)f2e4m3_sw(c) << 16) | ((unsigned)f2e4m3_sw(d) << 24);
#endif
}
DEV unsigned char enc_fp8(float a){
#ifdef HW_FP8
  return (unsigned char)(__builtin_amdgcn_cvt_pk_fp8_f32(a, a, 0, false) & 0xFF);
#else
  return f2e4m3_sw(a);
#endif
}
template<int SEL>
DEV float dec_fp8(unsigned u){
#ifdef HW_FP8
  return __builtin_amdgcn_cvt_f32_fp8((int)u, SEL);
#else
  return e4m32f_sw((u >> (SEL * 8)) & 0xFF);
#endif
}

// async global->LDS, 16B per lane; LDS dest is wave-uniform base + lane*16.
DEV void gload16(const void* g, void* l) {
  __builtin_amdgcn_global_load_lds(
      (const __attribute__((address_space(1))) unsigned*)g,
      (__attribute__((address_space(3))) unsigned*)l, 16, 0, 0);
}

// ---------------------------------------------------------------------------
// Both weight cvts in ONE dispatch: blockIdx.y selects Wq or Wk.
// ---------------------------------------------------------------------------
__global__ __launch_bounds__(256)
void cvt_wqk(const float* __restrict__ Wq, const float* __restrict__ Wk,
             ushort* __restrict__ Wq16, ushort* __restrict__ Wk16)
{
  const float* src = blockIdx.y ? Wk : Wq;
  ushort* dst = blockIdx.y ? Wk16 : Wq16;
  const long n8 = 1280l * 1280 / 8;
  const long stride = (long)gridDim.x * 256;
  for (long i = (long)blockIdx.x * 256 + threadIdx.x; i < n8; i += stride) {
    const float4 a = *(const float4*)(src + i * 8);
    const float4 b = *(const float4*)(src + i * 8 + 4);
    union { ushort u[8]; uint4 v; } pk;
    pk.u[0] = f2bf(a.x); pk.u[1] = f2bf(a.y); pk.u[2] = f2bf(a.z); pk.u[3] = f2bf(a.w);
    pk.u[4] = f2bf(b.x); pk.u[5] = f2bf(b.y); pk.u[6] = f2bf(b.z); pk.u[7] = f2bf(b.w);
    *(uint4*)(dst + i * 8) = pk.v;
  }
}

// cyclase: f32 row -> fp8 row (x16) + exact f32 rowsum. Wave per row.
__global__ __launch_bounds__(256)
void cyccvt(const float* __restrict__ cyc, unsigned* __restrict__ cyc8w,
            float* __restrict__ gsum)
{
  const int lane = threadIdx.x & 63, wid = threadIdx.x >> 6;
  const long row = (long)blockIdx.x * 4 + wid;   // 32768 rows
  const float* src = cyc + row * 1280;
  unsigned* dst = cyc8w + row * 320;
  float s = 0.f;
  #pragma unroll
  for (int i = 0; i < 5; i++) {
    const int d = i * 256 + lane * 4;
    const float4 v = *(const float4*)(src + d);
    s += v.x + v.y + v.z + v.w;
    dst[d >> 2] = pack4_fp8(v.x * 16.f, v.y * 16.f, v.z * 16.f, v.w * 16.f);
  }
  #pragma unroll
  for (int o = 1; o < 64; o <<= 1) s += __shfl_xor(s, o);
  if (lane == 0) gsum[row] = s;
}

// substrate fused pass: f32 row read ONCE -> sub8 (fp8 x16) + exact tbar.
__global__ __launch_bounds__(256)
void subprep(const float* __restrict__ sub, const float* __restrict__ mcol,
             unsigned* __restrict__ sub8w, float* __restrict__ tbar)
{
  __shared__ float mc[1280];
  for (int i = threadIdx.x; i < 1280; i += 256) mc[i] = mcol[i];
  __syncthreads();
  const int lane = threadIdx.x & 63, wid = threadIdx.x >> 6;
  const long row = (long)blockIdx.x * 4 + wid;   // 16384 rows
  const float4* sp = (const float4*)(sub + row * 1280);
  unsigned* dp = sub8w + row * 320;
  float d = 0.f;
  #pragma unroll
  for (int i = 0; i < 5; i++) {
    const int c = i * 64 + lane;
    const float4 v = sp[c];
    d += v.x * mc[c * 4] + v.y * mc[c * 4 + 1] + v.z * mc[c * 4 + 2] + v.w * mc[c * 4 + 3];
    dp[c] = pack4_fp8(v.x * 16.f, v.y * 16.f, v.z * 16.f, v.w * 16.f);
  }
  #pragma unroll
  for (int o = 1; o < 64; o <<= 1) d += __shfl_xor(d, o);
  if (lane == 0) tbar[row] = d;
}

// ---------------------------------------------------------------------------
// bf16 GEMM 8-phase (BM=128) — Mkq only. Epilogue also accumulates mcol
// (column means) via per-lane partial + atomicAdd: kills the colmean
// dispatch. mcol must be pre-zeroed. Decomposition stays self-consistent:
// m2cvt subtracts the SAME mcol from the bf16 C it reads.
// ---------------------------------------------------------------------------
__global__ __launch_bounds__(512, 4)
void gemm_mkq(const ushort* __restrict__ A, const ushort* __restrict__ B,
              ushort* __restrict__ C, int K, int N, int nbx, float scale,
              float* __restrict__ mcol)
{
  __shared__ __align__(16) ushort As[4][4][128][8];
  __shared__ __align__(16) ushort Bs[4][4][128][8];
  const int tid = threadIdx.x, lane = tid & 63, wid = tid >> 6;
  const int wr = wid >> 2, wc = wid & 3;
  const int bx = blockIdx.x % nbx, by = blockIdx.x / nbx;
  const int bm = by * 128, bn = bx * 128;

  f32x16 acc[2];
  #pragma unroll
  for (int i = 0; i < 2; i++)
    #pragma unroll
    for (int e = 0; e < 16; e++) acc[i][e] = 0.f;

  const int kbA = wid >> 1, rqA = wid & 1;
  const ushort* agp = A + (long)(bm + rqA * 64 + lane) * K + kbA * 8;
  const ushort* bgp = B + (long)(bn + rqA * 64 + lane) * K + kbA * 8;
  auto STAGE = [&](int g, int rg) {
    gload16(agp + g * 32, &As[rg][kbA][rqA * 64][0]);
    gload16(bgp + g * 32, &Bs[rg][kbA][rqA * 64][0]);
  };
  const int NG = K >> 5;
  STAGE(0, 0); STAGE(1, 1);
  asm volatile("s_waitcnt vmcnt(2)" ::: "memory");
  __builtin_amdgcn_s_barrier();
  const int lkh = lane >> 5, lr = lane & 31;
  auto GROUP = [&](int g, int rg, int rg2) {
    bf16x8 av[2][2], bv[2];
    #pragma unroll
    for (int kf = 0; kf < 2; kf++) {
      #pragma unroll
      for (int mi = 0; mi < 2; mi++)
        av[mi][kf] = *(const bf16x8*)&As[rg][kf * 2 + lkh][wr * 64 + mi * 32 + lr][0];
      bv[kf] = *(const bf16x8*)&Bs[rg][kf * 2 + lkh][wc * 32 + lr][0];
    }
    if (g + 2 < NG) STAGE(g + 2, rg2);
    __builtin_amdgcn_s_barrier();
    __builtin_amdgcn_s_setprio(1);
    #pragma unroll
    for (int mi = 0; mi < 2; mi++)
      #pragma unroll
      for (int kf = 0; kf < 2; kf++)
        acc[mi] = __builtin_amdgcn_mfma_f32_32x32x16_bf16(av[mi][kf], bv[kf], acc[mi], 0, 0, 0);
    __builtin_amdgcn_s_setprio(0);
    if (g + 2 < NG)      asm volatile("s_waitcnt vmcnt(2)" ::: "memory");
    else if (g + 1 < NG) asm volatile("s_waitcnt vmcnt(0)" ::: "memory");
    __builtin_amdgcn_s_barrier();
  };
  for (int g = 0; g < NG; g += 4) {
    GROUP(g, 0, 2); GROUP(g + 1, 1, 3); GROUP(g + 2, 2, 0); GROUP(g + 3, 3, 1);
  }
  float csum = 0.f;
  #pragma unroll
  for (int mi = 0; mi < 2; mi++)
    #pragma unroll
    for (int rr = 0; rr < 16; rr++) {
      const int row = bm + wr * 64 + mi * 32 + (rr & 3) + 8 * (rr >> 2) + 4 * lkh;
      const int col = bn + wc * 32 + lr;
      const float v = acc[mi][rr] * scale;
      csum += v;
      C[(long)row * N + col] = f2bf(v);
    }
  atomicAdd(&mcol[bn + wc * 32 + lr], csum * (1.f / 1280.f));
}

// M2_8[j][d] = e4m3((Mkq[j][d] - mcol[d]) * 2^19)
__global__ __launch_bounds__(320)
void m2cvt(const ushort* __restrict__ Mkq, const float* __restrict__ mcol,
           unsigned* __restrict__ M2w)
{
  const int j = blockIdx.x;
  const int d = threadIdx.x * 4;
  const ushort* mr = Mkq + (long)j * 1280 + d;
  const float* mc = mcol + d;
  M2w[j * 320 + threadIdx.x] = pack4_fp8(
      (bf2f(mr[0]) - mc[0]) * 524288.f, (bf2f(mr[1]) - mc[1]) * 524288.f,
      (bf2f(mr[2]) - mc[2]) * 524288.f, (bf2f(mr[3]) - mc[3]) * 524288.f);
}

// ---------------------------------------------------------------------------
// fp8 GEMM 256x256 (r10/r14 config — best measured): ring-4, depth-2,
// gload16, MFMA 32x32x16_fp8_fp8.
// MODE 0: C = bf16( acc*2^-16 + tbar[z*1024+row]*gsum[z*2048+col] )   (S)
// ---------------------------------------------------------------------------
template<int MODE, bool BY_FAST>
__global__ __launch_bounds__(512, 2)
void gemm_f8(const unsigned char* __restrict__ A, const unsigned char* __restrict__ B,
             void* __restrict__ Cv, int K, int N, int nbx, int nby,
             long sA, long sB, long sC,
             const float* __restrict__ tbar, const float* __restrict__ gsum)
{
  __shared__ __align__(16) unsigned char As[4][4][256][16];  // 64 KB
  __shared__ __align__(16) unsigned char Bs[4][4][256][16];  // 64 KB
  const int tid = threadIdx.x, lane = tid & 63, wid = tid >> 6;
  const int wr = wid >> 2, wc = wid & 3;

  const int nwg = gridDim.x;
  const int q = nwg >> 3, r = nwg & 7;
  const int xcd = blockIdx.x & 7, lid = blockIdx.x >> 3;
  const int id = (xcd < r ? xcd * (q + 1) : r * (q + 1) + (xcd - r) * q) + lid;
  const int per = nbx * nby;
  const int z = id / per, rem = id - z * per;
  const int bx = BY_FAST ? rem / nby : rem % nbx;
  const int by = BY_FAST ? rem % nby : rem / nbx;
  const int bm = by * 256, bn = bx * 256;
  const long Ab = (long)z * sA, Bb = (long)z * sB, Cb = (long)z * sC;

  f32x16 acc[4][2];
  #pragma unroll
  for (int i = 0; i < 4; i++)
    #pragma unroll
    for (int j = 0; j < 2; j++)
      #pragma unroll
      for (int e = 0; e < 16; e++) acc[i][j][e] = 0.f;

  const int c0 = wid * 2, c1 = wid * 2 + 1;
  const int kb0 = c0 >> 2, rq0 = c0 & 3, kb1 = c1 >> 2, rq1 = c1 & 3;
  const unsigned char* ag0 = A + Ab + (long)(bm + rq0 * 64 + lane) * K + kb0 * 16;
  const unsigned char* ag1 = A + Ab + (long)(bm + rq1 * 64 + lane) * K + kb1 * 16;
  const unsigned char* bg0 = B + Bb + (long)(bn + rq0 * 64 + lane) * K + kb0 * 16;
  const unsigned char* bg1 = B + Bb + (long)(bn + rq1 * 64 + lane) * K + kb1 * 16;
  auto STAGE_A = [&](int g, int rg) {
    gload16(ag0 + g * 64, &As[rg][kb0][rq0 * 64][0]);
    gload16(ag1 + g * 64, &As[rg][kb1][rq1 * 64][0]);
  };
  auto STAGE_B = [&](int g, int rg) {
    gload16(bg0 + g * 64, &Bs[rg][kb0][rq0 * 64][0]);
    gload16(bg1 + g * 64, &Bs[rg][kb1][rq1 * 64][0]);
  };

  const int NG = K >> 6;  // 64-K groups, multiple of 4
  STAGE_A(0, 0); STAGE_B(0, 0); STAGE_A(1, 1); STAGE_B(1, 1);
  asm volatile("s_waitcnt vmcnt(4)" ::: "memory");
  __builtin_amdgcn_s_barrier();

  const int lkh = lane >> 5, lr = lane & 31;

  auto GROUP = [&](int g, int rg, int rg2) {
    const bool pre = (g + 2 < NG);
    long av[2][4], bv[2][4];
    #pragma unroll
    for (int kf = 0; kf < 4; kf++) {
      #pragma unroll
      for (int mi = 0; mi < 2; mi++)
        av[mi][kf] = *(const long*)&As[rg][kf][wr * 128 + mi * 32 + lr][lkh * 8];
      #pragma unroll
      for (int ni = 0; ni < 2; ni++)
        bv[ni][kf] = *(const long*)&Bs[rg][kf][wc * 64 + ni * 32 + lr][lkh * 8];
    }
    if (pre) STAGE_A(g + 2, rg2);
    __builtin_amdgcn_s_barrier();
    __builtin_amdgcn_s_setprio(1);
    #pragma unroll
    for (int kf = 0; kf < 4; kf++)
      #pragma unroll
      for (int mi = 0; mi < 2; mi++)
        #pragma unroll
        for (int ni = 0; ni < 2; ni++)
          acc[mi][ni] = __builtin_amdgcn_mfma_f32_32x32x16_fp8_fp8(av[mi][kf], bv[ni][kf], acc[mi][ni], 0, 0, 0);
    __builtin_amdgcn_s_setprio(0);
    __builtin_amdgcn_s_barrier();
    #pragma unroll
    for (int kf = 0; kf < 4; kf++)
      #pragma unroll
      for (int mi = 0; mi < 2; mi++)
        av[mi][kf] = *(const long*)&As[rg][kf][wr * 128 + (mi + 2) * 32 + lr][lkh * 8];
    if (pre) STAGE_B(g + 2, rg2);
    __builtin_amdgcn_s_barrier();
    __builtin_amdgcn_s_setprio(1);
    #pragma unroll
    for (int kf = 0; kf < 4; kf++)
      #pragma unroll
      for (int mi = 0; mi < 2; mi++)
        #pragma unroll
        for (int ni = 0; ni < 2; ni++)
          acc[mi + 2][ni] = __builtin_amdgcn_mfma_f32_32x32x16_fp8_fp8(av[mi][kf], bv[ni][kf], acc[mi + 2][ni], 0, 0, 0);
    __builtin_amdgcn_s_setprio(0);
    if (pre)             asm volatile("s_waitcnt vmcnt(4)" ::: "memory");
    else if (g + 1 < NG) asm volatile("s_waitcnt vmcnt(0)" ::: "memory");
    __builtin_amdgcn_s_barrier();
  };

  for (int g = 0; g < NG; g += 4) {
    GROUP(g, 0, 2); GROUP(g + 1, 1, 3); GROUP(g + 2, 2, 0); GROUP(g + 3, 3, 1);
  }

  // C/D 32x32: col=lane&31, row=(reg&3)+8*(reg>>2)+4*(lane>>5)
  #pragma unroll
  for (int mi = 0; mi < 4; mi++)
    #pragma unroll
    for (int ni = 0; ni < 2; ni++)
      #pragma unroll
      for (int rr = 0; rr < 16; rr++) {
        const int row = bm + wr * 128 + mi * 32 + (rr & 3) + 8 * (rr >> 2) + 4 * lkh;
        const int col = bn + wc * 64 + ni * 32 + lr;
        if constexpr (MODE == 0) {
          const float v = acc[mi][ni][rr] * 0x1p-16f
                        + tbar[(long)z * 1024 + row] * gsum[(long)z * 2048 + col];
          ((ushort*)Cv)[Cb + (long)row * N + col] = f2bf(v);
        } else {
          ((unsigned char*)Cv)[Cb + (long)row * N + col] = enc_fp8(acc[mi][ni][rr] * 0x1p-11f);
        }
      }
}

// ---------------------------------------------------------------------------
// fp8 GEMM 128x128 (T1', r14 config): 2 blocks/CU, 1280 blocks = 5 rounds.
// C = e4m3( acc * 2^-11 ).
// ---------------------------------------------------------------------------
__global__ __launch_bounds__(512, 4)
void gemm_f8_128(const unsigned char* __restrict__ A, const unsigned char* __restrict__ B,
                 unsigned char* __restrict__ C, int K, int N, int nbx)
{
  __shared__ __align__(16) unsigned char As[4][4][128][16];  // 32 KB
  __shared__ __align__(16) unsigned char Bs[4][4][128][16];  // 32 KB
  const int tid = threadIdx.x, lane = tid & 63, wid = tid >> 6;
  const int wr = wid >> 2, wc = wid & 3;

  const int nwg = gridDim.x;
  const int q = nwg >> 3, r = nwg & 7;
  const int xcd = blockIdx.x & 7, lid = blockIdx.x >> 3;
  const int id = (xcd < r ? xcd * (q + 1) : r * (q + 1) + (xcd - r) * q) + lid;
  const int bx = id % nbx, by = id / nbx;
  const int bm = by * 128, bn = bx * 128;

  f32x16 acc[2];
  #pragma unroll
  for (int i = 0; i < 2; i++)
    #pragma unroll
    for (int e = 0; e < 16; e++) acc[i][e] = 0.f;

  const int kbA = wid >> 1, rhA = wid & 1;
  const unsigned char* agp = A + (long)(bm + rhA * 64 + lane) * K + kbA * 16;
  const unsigned char* bgp = B + (long)(bn + rhA * 64 + lane) * K + kbA * 16;
  auto STAGE = [&](int g, int rg) {
    gload16(agp + g * 64, &As[rg][kbA][rhA * 64][0]);
    gload16(bgp + g * 64, &Bs[rg][kbA][rhA * 64][0]);
  };
  const int NG = K >> 6;  // K=1280 -> 20
  STAGE(0, 0); STAGE(1, 1);
  asm volatile("s_waitcnt vmcnt(2)" ::: "memory");
  __builtin_amdgcn_s_barrier();

  const int lkh = lane >> 5, lr = lane & 31;

  auto GROUP = [&](int g, int rg, int rg2) {
    long av[2][4], bv[4];
    #pragma unroll
    for (int kf = 0; kf < 4; kf++) {
      #pragma unroll
      for (int mi = 0; mi < 2; mi++)
        av[mi][kf] = *(const long*)&As[rg][kf][wr * 64 + mi * 32 + lr][lkh * 8];
      bv[kf] = *(const long*)&Bs[rg][kf][wc * 32 + lr][lkh * 8];
    }
    if (g + 2 < NG) STAGE(g + 2, rg2);
    __builtin_amdgcn_s_barrier();
    __builtin_amdgcn_s_setprio(1);
    #pragma unroll
    for (int kf = 0; kf < 4; kf++)
      #pragma unroll
      for (int mi = 0; mi < 2; mi++)
        acc[mi] = __builtin_amdgcn_mfma_f32_32x32x16_fp8_fp8(av[mi][kf], bv[kf], acc[mi], 0, 0, 0);
    __builtin_amdgcn_s_setprio(0);
    if (g + 2 < NG)      asm volatile("s_waitcnt vmcnt(2)" ::: "memory");
    else if (g + 1 < NG) asm volatile("s_waitcnt vmcnt(0)" ::: "memory");
    __builtin_amdgcn_s_barrier();
  };
  for (int g = 0; g < NG; g += 4) {
    GROUP(g, 0, 2); GROUP(g + 1, 1, 3); GROUP(g + 2, 2, 0); GROUP(g + 3, 3, 1);
  }

  #pragma unroll
  for (int mi = 0; mi < 2; mi++)
    #pragma unroll
    for (int rr = 0; rr < 16; rr++) {
      const int row = bm + wr * 64 + mi * 32 + (rr & 3) + 8 * (rr >> 2) + 4 * lkh;
      const int col = bn + wc * 32 + lr;
      C[(long)row * N + col] = enc_fp8(acc[mi][rr] * 0x1p-11f);
    }
}

// ---------------------------------------------------------------------------
// Softmax over c per (b,s) row of S (bf16); wsum[b,c] += softmax row.
// Grid (16, 64): 4 waves x 4 rows = 16 rows/block (2x parallelism vs r17).
// ---------------------------------------------------------------------------
__global__ __launch_bounds__(256)
void softmax_wsum(const ushort* __restrict__ S, float* __restrict__ wsum)
{
  const int b = blockIdx.x;
  const int s0 = blockIdx.y * 16;
  const int lane = threadIdx.x & 63;
  const int w = threadIdx.x >> 6;
  __shared__ float red[4][2048];
  const ushort* Sb = S + (((long)b * 1024) + s0 + w * 4) * 2048;

  float acc[32];
  #pragma unroll
  for (int i = 0; i < 32; i++) acc[i] = 0.f;
  for (int r = 0; r < 4; r++) {
    const ushort* row = Sb + (long)r * 2048;
    float v[32];
    #pragma unroll
    for (int i = 0; i < 4; i++) {
      uint4 u = *(const uint4*)(row + i * 512 + lane * 8);
      const ushort* up = (const ushort*)&u;
      #pragma unroll
      for (int j = 0; j < 8; j++) v[i * 8 + j] = bf2f(up[j]);
    }
    float m = v[0];
    #pragma unroll
    for (int i = 1; i < 32; i++) m = fmaxf(m, v[i]);
    #pragma unroll
    for (int o = 1; o < 64; o <<= 1) m = fmaxf(m, __shfl_xor(m, o));
    float ssum = 0.f;
    #pragma unroll
    for (int i = 0; i < 32; i++) { v[i] = __expf(v[i] - m); ssum += v[i]; }
    #pragma unroll
    for (int o = 1; o < 64; o <<= 1) ssum += __shfl_xor(ssum, o);
    const float inv = 1.f / ssum;
    #pragma unroll
    for (int i = 0; i < 32; i++) acc[i] += v[i] * inv;
  }
  #pragma unroll
  for (int i = 0; i < 4; i++)
    #pragma unroll
    for (int j = 0; j < 8; j++)
      red[w][i * 512 + lane * 8 + j] = acc[i * 8 + j];
  __syncthreads();
  float* wb = wsum + b * 2048;
  #pragma unroll
  for (int k = 0; k < 8; k++) {
    const int c = k * 256 + threadIdx.x;
    atomicAdd(&wb[c], red[0][c] + red[1][c] + red[2][c] + red[3][c]);
  }
}

// t[b,d] = sum_c wsum[b,c] * cyc8[b,c,d]/16
__global__ __launch_bounds__(320)
void wcyc_kernel(const unsigned char* __restrict__ cyc8, const float* __restrict__ wsum,
                 float* __restrict__ t)
{
  const int b = blockIdx.x;
  const int c0 = blockIdx.y * 64;
  const int d = threadIdx.x * 4;
  const unsigned char* cb = cyc8 + ((long)b * 2048 + c0) * 1280 + d;
  const float* wb = wsum + b * 2048 + c0;
  float4 a = {0.f, 0.f, 0.f, 0.f};
  for (int c = 0; c < 64; c++) {
    const unsigned u = *(const unsigned*)(cb + (long)c * 1280);
    const float w = wb[c];
    a.x += w * dec_fp8<0>(u); a.y += w * dec_fp8<1>(u);
    a.z += w * dec_fp8<2>(u); a.w += w * dec_fp8<3>(u);
  }
  atomicAdd(&t[b * 1280 + d + 0], a.x * 0.0625f);
  atomicAdd(&t[b * 1280 + d + 1], a.y * 0.0625f);
  atomicAdd(&t[b * 1280 + d + 2], a.z * 0.0625f);
  atomicAdd(&t[b * 1280 + d + 3], a.w * 0.0625f);
}

// xcat[b, 1280+d] += partial mean over 64-s chunk (grid 16x16).
__global__ __launch_bounds__(320)
void submean8(const unsigned char* __restrict__ sub8, float* __restrict__ xcat)
{
  const int b = blockIdx.x;
  const int s0 = blockIdx.y * 64;
  const int d = threadIdx.x * 4;
  const unsigned char* sp = sub8 + ((long)b * 1024 + s0) * 1280 + d;
  float4 a = {0.f, 0.f, 0.f, 0.f};
  for (int s = 0; s < 64; s++) {
    const unsigned u = *(const unsigned*)(sp + (long)s * 1280);
    a.x += dec_fp8<0>(u); a.y += dec_fp8<1>(u);
    a.z += dec_fp8<2>(u); a.w += dec_fp8<3>(u);
  }
  const float k = 1.f / (16.f * 1024.f);
  atomicAdd(&xcat[b * 2560 + 1280 + d + 0], a.x * k);
  atomicAdd(&xcat[b * 2560 + 1280 + d + 1], a.y * k);
  atomicAdd(&xcat[b * 2560 + 1280 + d + 2], a.z * k);
  atomicAdd(&xcat[b * 2560 + 1280 + d + 3], a.w * k);
}

// ---------------------------------------------------------------------------
// xv_fused: xcat[b, dp] += (1/1024) * sum_d t[b,d] * Wv[d,dp]. Wv tile read
// once for all 16 batches. Grid (20, 5), 256 threads.
// ---------------------------------------------------------------------------
__global__ __launch_bounds__(256)
void xv_fused(const float* __restrict__ t, const float* __restrict__ Wv,
              float* __restrict__ xcat)
{
  const int dp0 = blockIdx.x * 64;
  const int d0 = blockIdx.y * 256;
  __shared__ float tl[16 * 256];
  __shared__ float red[4][64][16];
  for (int i = threadIdx.x; i < 16 * 256; i += 256) {
    const int b = i >> 8, d = i & 255;
    tl[i] = t[b * 1280 + d0 + d];
  }
  __syncthreads();
  const int dpi = threadIdx.x & 63;
  const int grp = threadIdx.x >> 6;
  float acc[16];
  #pragma unroll
  for (int b = 0; b < 16; b++) acc[b] = 0.f;
  for (int dd = 0; dd < 64; dd++) {
    const int d = grp * 64 + dd;
    const float w = Wv[(long)(d0 + d) * 1280 + dp0 + dpi];
    #pragma unroll
    for (int b = 0; b < 16; b++) acc[b] += w * tl[b * 256 + d];
  }
  #pragma unroll
  for (int b = 0; b < 16; b++) red[grp][dpi][b] = acc[b];
  __syncthreads();
  #pragma unroll
  for (int k = 0; k < 4; k++) {
    const int o = k * 256 + threadIdx.x;
    const int dp = o >> 4, b = o & 15;
    const float v = red[0][dp][b] + red[1][dp][b] + red[2][dp][b] + red[3][dp][b];
    atomicAdd(&xcat[b * 2560 + dp0 + dp], v * (1.f / 1024.f));
  }
}

// ---------------------------------------------------------------------------
// mlp1_fused: h1pre[b,j] += sum_d xcat[b,d] * W1[d,j]. W1 tile read once
// for all 16 batches. Grid (8, 8), 256 threads.
// ---------------------------------------------------------------------------
__global__ __launch_bounds__(256)
void mlp1_fused(const float* __restrict__ xcat, const float* __restrict__ W1,
                float* __restrict__ h1pre)
{
  const int j0 = blockIdx.x * 64;
  const int d0 = blockIdx.y * 320;
  __shared__ float xl[16 * 320];
  __shared__ float red[4][64][16];
  for (int i = threadIdx.x; i < 16 * 320; i += 256) {
    const int b = i / 320, d = i % 320;
    xl[i] = xcat[b * 2560 + d0 + d];
  }
  __syncthreads();
  const int ji = threadIdx.x & 63;
  const int grp = threadIdx.x >> 6;
  float acc[16];
  #pragma unroll
  for (int b = 0; b < 16; b++) acc[b] = 0.f;
  for (int dd = 0; dd < 80; dd++) {
    const int d = grp * 80 + dd;
    const float w = W1[(long)(d0 + d) * 512 + j0 + ji];
    #pragma unroll
    for (int b = 0; b < 16; b++) acc[b] += w * xl[b * 320 + d];
  }
  #pragma unroll
  for (int b = 0; b < 16; b++) red[grp][ji][b] = acc[b];
  __syncthreads();
  #pragma unroll
  for (int k = 0; k < 4; k++) {
    const int o = k * 256 + threadIdx.x;
    const int j = o >> 4, b = o & 15;
    const float v = red[0][j][b] + red[1][j][b] + red[2][j][b] + red[3][j][b];
    atomicAdd(&h1pre[b * 512 + j0 + j], v);
  }
}

// h = relu(h1pre + b1); h2 = relu(h @ W2 + b2); out = sigmoid(h2 @ W3 + b3)
__global__ __launch_bounds__(64)
void mlp23_kernel(const float* __restrict__ h1pre, const float* __restrict__ b1,
                  const float* __restrict__ W2, const float* __restrict__ b2,
                  const float* __restrict__ W3, const float* __restrict__ b3,
                  float* __restrict__ out)
{
  const int b = blockIdx.x;
  const int j = threadIdx.x;
  __shared__ float hl[512];
  for (int i = j; i < 512; i += 64) hl[i] = fmaxf(h1pre[b * 512 + i] + b1[i], 0.f);
  __syncthreads();
  float a = b2[j];
  for (int d = 0; d < 512; d++) a += hl[d] * W2[d * 64 + j];
  a = fmaxf(a, 0.f);
  float p = a * W3[j];
  #pragma unroll
  for (int o = 1; o < 64; o <<= 1) p += __shfl_xor(p, o);
  if (j == 0) out[b] = 1.f / (1.f + __expf(-(p + b3[0])));
}

extern "C" void kernel_launch(void* const* d_in, const int* in_sizes, int n_in,
                              void* d_out, int out_size, void* d_ws, size_t ws_size,
                              hipStream_t stream)
{
  const float* cyclase   = (const float*)d_in[0];
  const float* substrate = (const float*)d_in[1];
  const float* Wq = (const float*)d_in[4];
  const float* Wk = (const float*)d_in[5];
  const float* Wv = (const float*)d_in[6];
  const float* W1 = (const float*)d_in[7];
  const float* b1 = (const float*)d_in[8];
  const float* W2 = (const float*)d_in[9];
  const float* b2 = (const float*)d_in[10];
  const float* W3 = (const float*)d_in[11];
  const float* b3 = (const float*)d_in[12];
  float* out = (float*)d_out;
  (void)in_sizes; (void)n_in; (void)out_size; (void)ws_size;

  char* ws = (char*)d_ws;
  unsigned char* cyc8 = (unsigned char*)ws;
  char* A2 = ws + 41943040;
  ushort* Mkq   = (ushort*)(A2 + 41943040);
  ushort* Wq16  = (ushort*)(A2 + 41943040 + 3276800);
  ushort* Wk16  = (ushort*)(A2 + 41943040 + 2 * 3276800);
  unsigned char* sub8 = (unsigned char*)(A2 + 41943040 + 3 * 3276800);
  ushort* S = (ushort*)A2;                       // overlays region2
  char* B2 = A2 + 41943040 + 3 * 3276800 + 20971520;
  unsigned char* T1p8 = (unsigned char*)B2;
  unsigned char* M2_8 = (unsigned char*)(B2 + 20971520);
  char* C2 = B2 + 20971520 + 1638400;
  float* mcol  = (float*)C2;
  float* tbar  = (float*)(C2 + 8192);
  float* gsum  = (float*)(C2 + 8192 + 65536);
  float* wsum  = (float*)(C2 + 8192 + 65536 + 131072);
  float* tbuf  = (float*)(C2 + 8192 + 65536 + 2 * 131072);
  float* xcat  = (float*)(C2 + 8192 + 65536 + 2 * 131072 + 81920);
  float* h1pre = (float*)(C2 + 8192 + 65536 + 2 * 131072 + 81920 + 163840);

  // ONE memset covers mcol..h1pre (contiguous small-buffer region, 614400 B;
  // tbar/gsum are fully overwritten later — zeroing them is harmless).
  hipMemsetAsync(C2, 0, 8192 + 65536 + 2 * 131072 + 81920 + 163840 + 32768, stream);

  cvt_wqk<<<dim3(200, 2), 256, 0, stream>>>(Wq, Wk, Wq16, Wk16);
  cyccvt<<<8192, 256, 0, stream>>>(cyclase, (unsigned*)cyc8, gsum);

  // Mkq = Wk @ Wq^T * (1/sqrt(1280)); epilogue accumulates mcol.
  gemm_mkq<<<100, 512, 0, stream>>>(Wk16, Wq16, Mkq, 1280, 1280, 10,
                                    0.02795084971874737f, mcol);
  m2cvt<<<1280, 320, 0, stream>>>(Mkq, mcol, (unsigned*)M2_8);

  // fused substrate pass: sub8 + exact tbar in one 84 MB read
  subprep<<<4096, 256, 0, stream>>>(substrate, mcol, (unsigned*)sub8, tbar);
  submean8<<<dim3(16, 16), 320, 0, stream>>>(sub8, xcat);

  // T1' = sub8 @ M2_8^T -> fp8 x4096   [16384,1280]
  gemm_f8_128<<<1280, 512, 0, stream>>>(sub8, M2_8, T1p8, 1280, 1280, 10);

  // S[b] = T1'8 @ cyc8^T * 2^-16 + tbar x gsum -> bf16  [16,1024,2048]
  gemm_f8<0, true><<<512, 512, 0, stream>>>(T1p8, cyc8, S,
      1280, 2048, 8, 4, 1024l * 1280, 2048l * 1280, 1024l * 2048, tbar, gsum);

  softmax_wsum<<<dim3(16, 64), 256, 0, stream>>>(S, wsum);
  wcyc_kernel<<<dim3(16, 32), 320, 0, stream>>>(cyc8, wsum, tbuf);
  xv_fused<<<dim3(20, 5), 256, 0, stream>>>(tbuf, Wv, xcat);
  mlp1_fused<<<dim3(8, 8), 256, 0, stream>>>(xcat, W1, h1pre);
  mlp23_kernel<<<16, 64, 0, stream>>>(h1pre, b1, W2, b2, W3, b3, out);
}